// Round 4
// baseline (495.446 us; speedup 1.0000x reference)
//
#include <hip/hip_runtime.h>
#include <hip/hip_bf16.h>

// ---------------------------------------------------------------------------
// AfmoE MoE: routing (sigmoid top-8) + 16 routed SwiGLU experts + shared
// expert as expert #16 via gather lists.
// Round 7: atomic-free two-phase routing (was 112us of serialized atomics).
// Round 8: 128x128 tile BK=64 GEMMs + LDS quad-swizzle (87->79us gateup).
// Round 9 (this round):
//   - gateup 3 blocks/CU (3x48.5KB=145.5<=160KB LDS), down 4 blocks/CU:
//     round-8 ran 2/CU -> 2 waves/SIMD, too little TLP to hide barrier
//     drain (490 TF observed vs ~800 expected).
//   - wconv rewritten with 8 independent coalesced float4 loads/thread:
//     was 1 load+1 store per thread = latency-bound at 3.9 TB/s combined.
// ---------------------------------------------------------------------------

typedef __attribute__((ext_vector_type(8))) short bf16x8;
typedef __attribute__((ext_vector_type(4))) float f32x4;

#define NTOK 1024   // B*S
#define DD   1024   // hidden
#define II   1024   // intermediate (same for shared)
#define NE   16     // routed experts
#define NEXP 17     // + shared expert as index 16
#define KSEL 8
#define RSCALE 2.826f

// fallback-path tiling
#define BM 128
#define BN 64
#define BK 32
#define LDA 40

// workspace layout (bytes)
#define MB (1024ull*1024ull)
#define OFF_XBF   0ull                         // ushort[NTOK*DD]          2 MiB
#define OFF_H     (2ull*MB)                    // ushort[NEXP*NTOK*II]    34 MiB
#define OFF_WG    (36ull*MB)                   // ushort[NEXP*II*DD]      34 MiB
#define OFF_WU    (70ull*MB)                   // ushort[NEXP*II*DD]      34 MiB
#define OFF_WD    (104ull*MB)                  // ushort[NEXP*DD*II]      34 MiB
#define OFF_LIST  (138ull*MB)                  // int[NEXP*NTOK]
#define OFF_SCALE (OFF_LIST + 4ull*NEXP*NTOK)  // float[NEXP*NTOK]
#define OFF_CNT   (OFF_SCALE + 4ull*NEXP*NTOK) // int[NEXP]
#define WS_NEED   (OFF_CNT + 4096ull)
// routing scratch aliased into the hbuf region (dead before gateup writes it):
//   emask: uint[NTOK] at OFF_H, tsc: float[NTOK*NE] at OFF_H+4096

__device__ __forceinline__ unsigned short f2bf(float f) {
    union { __hip_bfloat16 h; unsigned short u; } c;
    c.h = __float2bfloat16(f);
    return c.u;
}

__device__ __forceinline__ void gl2lds16(const unsigned short* g, unsigned short* l) {
    __builtin_amdgcn_global_load_lds(
        (const __attribute__((address_space(1))) void*)g,
        (__attribute__((address_space(3))) void*)l, 16, 0, 0);
}

// --- convert x to bf16; init shared-expert list/scale/count -----------------
__global__ __launch_bounds__(256) void prep_kernel(
    const float* __restrict__ x, unsigned short* __restrict__ xbf,
    int* __restrict__ list, float* __restrict__ scalebuf, int* __restrict__ count)
{
    int idx = blockIdx.x * 256 + threadIdx.x;
    float4 v = ((const float4*)x)[idx];
    ((ushort4*)xbf)[idx] = make_ushort4(f2bf(v.x), f2bf(v.y), f2bf(v.z), f2bf(v.w));
    if (idx < NTOK) { list[NE * NTOK + idx] = idx; scalebuf[NE * NTOK + idx] = 1.0f; }
    if (idx == 0) count[NE] = NTOK;
}

// --- convert all expert weights fp32 -> bf16 pools -------------------------
// 8 independent coalesced float4 loads per thread (ILP): idx = base + c*256 + tid
__global__ __launch_bounds__(256) void wconv_kernel(
    const float* __restrict__ wg, const float* __restrict__ wu, const float* __restrict__ wd,
    const float* __restrict__ sgw, const float* __restrict__ suw, const float* __restrict__ sdw,
    unsigned short* __restrict__ wgb, unsigned short* __restrict__ wub,
    unsigned short* __restrict__ wdb)
{
    const size_t ROUTED4 = (size_t)NE * II * DD / 4;
    int p = blockIdx.y;
    const float* rsrc = (p == 0) ? wg : (p == 1) ? wu : wd;
    const float* ssrc = (p == 0) ? sgw : (p == 1) ? suw : sdw;
    unsigned short* dst = (p == 0) ? wgb : (p == 1) ? wub : wdb;

    size_t base = (size_t)blockIdx.x * 2048 + threadIdx.x;
    float4 v[8];
#pragma unroll
    for (int c = 0; c < 8; c++) {
        size_t i4 = base + c * 256;
        const float* src = (i4 < ROUTED4) ? rsrc + 4 * i4 : ssrc + 4 * (i4 - ROUTED4);
        v[c] = *(const float4*)src;
    }
#pragma unroll
    for (int c = 0; c < 8; c++) {
        size_t i4 = base + c * 256;
        ((ushort4*)dst)[i4] = make_ushort4(f2bf(v[c].x), f2bf(v[c].y), f2bf(v[c].z), f2bf(v[c].w));
    }
}

// --- routing phase 1: scores + top-8 -> bitmask + scales (no atomics) ------
__global__ __launch_bounds__(256) void route_score_kernel(
    const float* __restrict__ x, const float* __restrict__ gw,
    const float* __restrict__ bias,
    unsigned int* __restrict__ emask, float* __restrict__ tsc)
{
    int wave = threadIdx.x >> 6, lane = threadIdx.x & 63;
    int t = blockIdx.x * 4 + wave;

    const float4* xr = (const float4*)(x + (size_t)t * DD);
    float acc[NE];
#pragma unroll
    for (int e = 0; e < NE; e++) acc[e] = 0.f;
#pragma unroll
    for (int i = 0; i < DD / 64 / 4; i++) {
        float4 xv = xr[lane + 64 * i];
#pragma unroll
        for (int e = 0; e < NE; e++) {
            float4 w = ((const float4*)(gw + (size_t)e * DD))[lane + 64 * i];
            acc[e] += xv.x * w.x + xv.y * w.y + xv.z * w.z + xv.w * w.w;
        }
    }
#pragma unroll
    for (int e = 0; e < NE; e++) {
        float v = acc[e];
        for (int off = 32; off > 0; off >>= 1) v += __shfl_xor(v, off, 64);
        acc[e] = v;
    }
    if (lane == 0) {
        float sc[NE], sel[NE];
#pragma unroll
        for (int e = 0; e < NE; e++) {
            sc[e] = 1.f / (1.f + expf(-acc[e]));
            sel[e] = sc[e] + bias[e];
        }
        bool used[NE] = {};
        int inds[KSEL];
        float ssum = 0.f;
        for (int k = 0; k < KSEL; k++) {
            float best = -1e30f; int bi = 0;
            for (int e = 0; e < NE; e++)
                if (!used[e] && sel[e] > best) { best = sel[e]; bi = e; }
            used[bi] = true; inds[k] = bi; ssum += sc[bi];
        }
        float inv = RSCALE / ssum;
        unsigned int m = 0;
        for (int k = 0; k < KSEL; k++) {
            int e = inds[k];
            m |= (1u << e);
            tsc[(size_t)t * NE + e] = sc[e] * inv;
        }
        emask[t] = m;
    }
}

// --- routing phase 2: per-expert gather lists via ballot prefix-scan -------
__global__ __launch_bounds__(1024) void build_lists_kernel(
    const unsigned int* __restrict__ emask, const float* __restrict__ tsc,
    int* __restrict__ count, int* __restrict__ list, float* __restrict__ scalebuf)
{
    int e = blockIdx.x;
    int t = threadIdx.x;
    int lane = t & 63, wave = t >> 6;
    bool sel = (emask[t] >> e) & 1u;
    unsigned long long m = __ballot(sel);
    int posw = __popcll(m & ((1ull << lane) - 1ull));
    int wtot = __popcll(m);
    __shared__ int woff[16];
    if (lane == 0) woff[wave] = wtot;
    __syncthreads();
    if (t == 0) {
        int s = 0;
#pragma unroll
        for (int w = 0; w < 16; w++) { int v = woff[w]; woff[w] = s; s += v; }
        count[e] = s;
    }
    __syncthreads();
    if (sel) {
        int pos = woff[wave] + posw;
        list[e * NTOK + pos] = t;
        scalebuf[e * NTOK + pos] = tsc[(size_t)t * NE + e];
    }
}

// --- fused gate+up GEMM: BM=128 BN=128 BK=64, XCD-swizzled 1-D grid --------
// grid 1088 = 17 experts x 8 n-tiles x 8 m-tiles. slot decode puts all 8
// m-tiles of one (e,n0) on one XCD (slot&7) for L2 weight reuse.
// LDS per K-step buffer: [q(2)][row(128)][32 elems] = 16 KB, x3 buffers.
// Quad-swizzle: LDS[row][chunk j] holds global chunk j^((row>>1)&3); staging
// pre-swizzles the global source column, gl2lds dest stays linear.
// 3 blocks/CU (145.5 KB LDS of 160).
__global__ __launch_bounds__(256, 3) void gateup_kernel(
    const unsigned short* __restrict__ xbf,
    const unsigned short* __restrict__ wgb, const unsigned short* __restrict__ wub,
    const int* __restrict__ count, const int* __restrict__ list,
    const float* __restrict__ scalebuf, unsigned short* __restrict__ hbuf)
{
    int s = blockIdx.x;
    int xcd = s & 7, t = s >> 3;
    int g = xcd + 8 * (t >> 3);          // (e,n0) group, g%8 == xcd
    int e = g >> 3;
    int n0 = (g & 7) * 128;
    int m0 = (t & 7) * 128;
    int cnt = count[e];
    if (m0 >= cnt) return;
    const unsigned short* Bg = wgb + (size_t)e * II * DD;
    const unsigned short* Bu = wub + (size_t)e * II * DD;

    __shared__ __align__(16) unsigned short As[8192];
    __shared__ __align__(16) unsigned short Bgs[8192];
    __shared__ __align__(16) unsigned short Bus[8192];
    __shared__ int rowtok[128];

    int tid = threadIdx.x;
    if (tid < 128) {
        int gr = m0 + tid;
        rowtok[tid] = list[e * NTOK + ((gr < cnt) ? gr : (cnt - 1))];
    }
    __syncthreads();

    int lane = tid & 63, wave = tid >> 6;
    int wm = wave & 1, wn = wave >> 1;
    int row16 = lane & 15, quad = lane >> 4;

    // staging geometry: wave covers q = wave>>1, rows (wave&1)*64 + c*16 + (lane>>2)
    int qS = wave >> 1;
    int srow = (wave & 1) * 64 + (lane >> 2);          // + c*16
    int colS = ((lane & 3) ^ ((lane >> 3) & 3)) * 8;   // pre-swizzled source chunk
    int tokr[4];
#pragma unroll
    for (int c = 0; c < 4; c++) tokr[c] = rowtok[srow + c * 16];
    const unsigned short* gBg0 = Bg + (size_t)(n0 + srow) * DD + colS;
    const unsigned short* gBu0 = Bu + (size_t)(n0 + srow) * DD + colS;

    f32x4 accG[4][4], accU[4][4];
#pragma unroll
    for (int mi = 0; mi < 4; mi++)
#pragma unroll
        for (int ni = 0; ni < 4; ni++) {
            accG[mi][ni] = (f32x4){0.f, 0.f, 0.f, 0.f};
            accU[mi][ni] = (f32x4){0.f, 0.f, 0.f, 0.f};
        }

    int qe = (quad ^ ((row16 >> 1) & 3)) * 8;          // swizzled read chunk

    for (int k0 = 0; k0 < DD; k0 += 64) {
        int koff = k0 + qS * 32;
#pragma unroll
        for (int c = 0; c < 4; c++) {
            gl2lds16(xbf + (size_t)tokr[c] * DD + koff + colS, As + wave * 2048 + c * 512);
            gl2lds16(gBg0 + (size_t)(c * 16) * DD + koff, Bgs + wave * 2048 + c * 512);
            gl2lds16(gBu0 + (size_t)(c * 16) * DD + koff, Bus + wave * 2048 + c * 512);
        }
        __syncthreads();

#pragma unroll
        for (int kk = 0; kk < 2; kk++) {
            bf16x8 a[4], bg[4], bu[4];
            int base = kk * 4096 + qe;
#pragma unroll
            for (int mi = 0; mi < 4; mi++)
                a[mi] = *(const bf16x8*)(As + base + (wm * 64 + mi * 16 + row16) * 32);
#pragma unroll
            for (int ni = 0; ni < 4; ni++) {
                bg[ni] = *(const bf16x8*)(Bgs + base + (wn * 64 + ni * 16 + row16) * 32);
                bu[ni] = *(const bf16x8*)(Bus + base + (wn * 64 + ni * 16 + row16) * 32);
            }
#pragma unroll
            for (int mi = 0; mi < 4; mi++)
#pragma unroll
                for (int ni = 0; ni < 4; ni++) {
                    accG[mi][ni] = __builtin_amdgcn_mfma_f32_16x16x32_bf16(a[mi], bg[ni], accG[mi][ni], 0, 0, 0);
                    accU[mi][ni] = __builtin_amdgcn_mfma_f32_16x16x32_bf16(a[mi], bu[ni], accU[mi][ni], 0, 0, 0);
                }
        }
        __syncthreads();
    }

    // epilogue: silu(g)*u * route_scale -> bf16 h
#pragma unroll
    for (int mi = 0; mi < 4; mi++) {
        int grb = m0 + wm * 64 + mi * 16 + quad * 4;
#pragma unroll
        for (int r = 0; r < 4; r++) {
            int gr = grb + r;
            if (gr >= cnt) continue;
            float rs = scalebuf[e * NTOK + gr];
            size_t rowoff = ((size_t)e * NTOK + gr) * II + n0 + wn * 64;
#pragma unroll
            for (int ni = 0; ni < 4; ni++) {
                float g2 = accG[mi][ni][r], u = accU[mi][ni][r];
                float h = g2 / (1.f + __expf(-g2)) * u * rs;
                hbuf[rowoff + ni * 16 + row16] = f2bf(h);
            }
        }
    }
}

// --- down GEMM: BM=128 BN=128 BK=64, XCD-swizzled; atomic scatter into y ---
// 4 blocks/CU (130 KB LDS of 160).
__global__ __launch_bounds__(256, 4) void down_kernel(
    const unsigned short* __restrict__ hbuf,
    const unsigned short* __restrict__ wdb,
    const int* __restrict__ count, const int* __restrict__ list,
    float* __restrict__ y)
{
    int s = blockIdx.x;
    int xcd = s & 7, t = s >> 3;
    int g = xcd + 8 * (t >> 3);
    int e = g >> 3;
    int n0 = (g & 7) * 128;
    int m0 = (t & 7) * 128;
    int cnt = count[e];
    if (m0 >= cnt) return;
    const unsigned short* Bp = wdb + (size_t)e * DD * II;

    __shared__ __align__(16) unsigned short As[8192];
    __shared__ __align__(16) unsigned short Bs[8192];

    int tid = threadIdx.x;
    int lane = tid & 63, wave = tid >> 6;
    int wm = wave & 1, wn = wave >> 1;
    int row16 = lane & 15, quad = lane >> 4;

    int qS = wave >> 1;
    int srow = (wave & 1) * 64 + (lane >> 2);
    int colS = ((lane & 3) ^ ((lane >> 3) & 3)) * 8;

    size_t arow[4];
#pragma unroll
    for (int c = 0; c < 4; c++) {
        int gr = m0 + srow + c * 16;
        int idx = (gr < cnt) ? gr : (cnt - 1);   // clamp: garbage rows skipped in epilogue
        arow[c] = ((size_t)e * NTOK + idx) * II;
    }
    const unsigned short* gB0 = Bp + (size_t)(n0 + srow) * II + colS;

    f32x4 acc[4][4];
#pragma unroll
    for (int mi = 0; mi < 4; mi++)
#pragma unroll
        for (int ni = 0; ni < 4; ni++) acc[mi][ni] = (f32x4){0.f, 0.f, 0.f, 0.f};

    int qe = (quad ^ ((row16 >> 1) & 3)) * 8;

    for (int k0 = 0; k0 < II; k0 += 64) {
        int koff = k0 + qS * 32;
#pragma unroll
        for (int c = 0; c < 4; c++) {
            gl2lds16(hbuf + arow[c] + koff + colS, As + wave * 2048 + c * 512);
            gl2lds16(gB0 + (size_t)(c * 16) * II + koff, Bs + wave * 2048 + c * 512);
        }
        __syncthreads();

#pragma unroll
        for (int kk = 0; kk < 2; kk++) {
            bf16x8 a[4], b[4];
            int base = kk * 4096 + qe;
#pragma unroll
            for (int mi = 0; mi < 4; mi++)
                a[mi] = *(const bf16x8*)(As + base + (wm * 64 + mi * 16 + row16) * 32);
#pragma unroll
            for (int ni = 0; ni < 4; ni++)
                b[ni] = *(const bf16x8*)(Bs + base + (wn * 64 + ni * 16 + row16) * 32);
#pragma unroll
            for (int mi = 0; mi < 4; mi++)
#pragma unroll
                for (int ni = 0; ni < 4; ni++)
                    acc[mi][ni] = __builtin_amdgcn_mfma_f32_16x16x32_bf16(a[mi], b[ni], acc[mi][ni], 0, 0, 0);
        }
        __syncthreads();
    }

#pragma unroll
    for (int mi = 0; mi < 4; mi++) {
        int grb = m0 + wm * 64 + mi * 16 + quad * 4;
#pragma unroll
        for (int r = 0; r < 4; r++) {
            int gr = grb + r;
            if (gr >= cnt) continue;
            int tk = list[e * NTOK + gr];
            float* yr = y + (size_t)tk * DD + n0 + wn * 64;
#pragma unroll
            for (int ni = 0; ni < 4; ni++)
                unsafeAtomicAdd(yr + ni * 16 + row16, acc[mi][ni][r]);
        }
    }
}

// ======================= fallback path (round-0 kernels) ====================
__global__ __launch_bounds__(256) void gateup_fb(
    const unsigned short* __restrict__ xbf,
    const float* __restrict__ wg, const float* __restrict__ wu,
    const float* __restrict__ sgw, const float* __restrict__ suw,
    const int* __restrict__ count, const int* __restrict__ list,
    const float* __restrict__ scalebuf, unsigned short* __restrict__ hbuf)
{
    int e = blockIdx.z;
    int cnt = count[e];
    int m0 = blockIdx.x * BM;
    if (m0 >= cnt) return;
    int n0 = blockIdx.y * BN;
    const float* Bg = (e < NE) ? wg + (size_t)e * II * DD : sgw;
    const float* Bu = (e < NE) ? wu + (size_t)e * II * DD : suw;

    __shared__ __align__(16) unsigned short As[BM * LDA];
    __shared__ __align__(16) unsigned short Bgs[BN * LDA];
    __shared__ __align__(16) unsigned short Bus[BN * LDA];
    __shared__ int rowtok[BM];

    int tid = threadIdx.x;
    if (tid < BM) {
        int gr = m0 + tid;
        rowtok[tid] = (gr < cnt) ? list[e * NTOK + gr] : -1;
    }
    __syncthreads();

    int lane = tid & 63, wave = tid >> 6;
    int wm = wave >> 1, wn = wave & 1;
    int row16 = lane & 15, quad = lane >> 4;

    f32x4 accG[4][2], accU[4][2];
#pragma unroll
    for (int mi = 0; mi < 4; mi++)
#pragma unroll
        for (int ni = 0; ni < 2; ni++) {
            accG[mi][ni] = (f32x4){0.f, 0.f, 0.f, 0.f};
            accU[mi][ni] = (f32x4){0.f, 0.f, 0.f, 0.f};
        }

    for (int k0 = 0; k0 < DD; k0 += BK) {
#pragma unroll
        for (int i = 0; i < 2; i++) {
            int c = tid + 256 * i;
            int row = c >> 2, kc = (c & 3) * 8;
            int tok = rowtok[row];
            uint4 v = (tok >= 0) ? *(const uint4*)(xbf + (size_t)tok * DD + k0 + kc)
                                 : make_uint4(0u, 0u, 0u, 0u);
            *(uint4*)(As + row * LDA + kc) = v;
        }
#pragma unroll
        for (int i = 0; i < 2; i++) {
            int c = tid + 256 * i;
            int row = c >> 3, f = (c & 7) * 4;
            float4 vg = *(const float4*)(Bg + (size_t)(n0 + row) * DD + k0 + f);
            float4 vu = *(const float4*)(Bu + (size_t)(n0 + row) * DD + k0 + f);
            *(ushort4*)(Bgs + row * LDA + f) = make_ushort4(f2bf(vg.x), f2bf(vg.y), f2bf(vg.z), f2bf(vg.w));
            *(ushort4*)(Bus + row * LDA + f) = make_ushort4(f2bf(vu.x), f2bf(vu.y), f2bf(vu.z), f2bf(vu.w));
        }
        __syncthreads();

        bf16x8 af[4], bg[2], bu[2];
#pragma unroll
        for (int mi = 0; mi < 4; mi++)
            af[mi] = *(const bf16x8*)(As + (wm * 64 + mi * 16 + row16) * LDA + quad * 8);
#pragma unroll
        for (int ni = 0; ni < 2; ni++) {
            bg[ni] = *(const bf16x8*)(Bgs + (wn * 32 + ni * 16 + row16) * LDA + quad * 8);
            bu[ni] = *(const bf16x8*)(Bus + (wn * 32 + ni * 16 + row16) * LDA + quad * 8);
        }
#pragma unroll
        for (int mi = 0; mi < 4; mi++)
#pragma unroll
            for (int ni = 0; ni < 2; ni++) {
                accG[mi][ni] = __builtin_amdgcn_mfma_f32_16x16x32_bf16(af[mi], bg[ni], accG[mi][ni], 0, 0, 0);
                accU[mi][ni] = __builtin_amdgcn_mfma_f32_16x16x32_bf16(af[mi], bu[ni], accU[mi][ni], 0, 0, 0);
            }
        __syncthreads();
    }

#pragma unroll
    for (int mi = 0; mi < 4; mi++) {
        int mbase = wm * 64 + mi * 16 + quad * 4;
#pragma unroll
        for (int r = 0; r < 4; r++) {
            int gr = m0 + mbase + r;
            if (gr >= cnt) continue;
            float rs = scalebuf[e * NTOK + gr];
            size_t rowoff = ((size_t)e * NTOK + gr) * II + n0;
#pragma unroll
            for (int ni = 0; ni < 2; ni++) {
                int n = wn * 32 + ni * 16 + row16;
                float g = accG[mi][ni][r], u = accU[mi][ni][r];
                float h = g / (1.f + __expf(-g)) * u * rs;
                hbuf[rowoff + n] = f2bf(h);
            }
        }
    }
}

__global__ __launch_bounds__(256) void down_fb(
    const unsigned short* __restrict__ hbuf,
    const float* __restrict__ wd, const float* __restrict__ sdw,
    const int* __restrict__ count, const int* __restrict__ list,
    float* __restrict__ y)
{
    int e = blockIdx.z;
    int cnt = count[e];
    int m0 = blockIdx.x * BM;
    if (m0 >= cnt) return;
    int n0 = blockIdx.y * BN;
    const float* Bp = (e < NE) ? wd + (size_t)e * DD * II : sdw;

    __shared__ __align__(16) unsigned short As[BM * LDA];
    __shared__ __align__(16) unsigned short Bs[BN * LDA];

    int tid = threadIdx.x;
    int lane = tid & 63, wave = tid >> 6;
    int wm = wave >> 1, wn = wave & 1;
    int row16 = lane & 15, quad = lane >> 4;

    f32x4 acc[4][2];
#pragma unroll
    for (int mi = 0; mi < 4; mi++)
#pragma unroll
        for (int ni = 0; ni < 2; ni++) acc[mi][ni] = (f32x4){0.f, 0.f, 0.f, 0.f};

    const unsigned short* Abase = hbuf + ((size_t)e * NTOK + m0) * II;

    for (int k0 = 0; k0 < II; k0 += BK) {
#pragma unroll
        for (int i = 0; i < 2; i++) {
            int c = tid + 256 * i;
            int row = c >> 2, kc = (c & 3) * 8;
            uint4 v = (m0 + row < cnt) ? *(const uint4*)(Abase + (size_t)row * II + k0 + kc)
                                       : make_uint4(0u, 0u, 0u, 0u);
            *(uint4*)(As + row * LDA + kc) = v;
        }
#pragma unroll
        for (int i = 0; i < 2; i++) {
            int c = tid + 256 * i;
            int row = c >> 3, f = (c & 7) * 4;
            float4 v = *(const float4*)(Bp + (size_t)(n0 + row) * II + k0 + f);
            *(ushort4*)(Bs + row * LDA + f) = make_ushort4(f2bf(v.x), f2bf(v.y), f2bf(v.z), f2bf(v.w));
        }
        __syncthreads();

        bf16x8 af[4], bf[2];
#pragma unroll
        for (int mi = 0; mi < 4; mi++)
            af[mi] = *(const bf16x8*)(As + (wm * 64 + mi * 16 + row16) * LDA + quad * 8);
#pragma unroll
        for (int ni = 0; ni < 2; ni++)
            bf[ni] = *(const bf16x8*)(Bs + (wn * 32 + ni * 16 + row16) * LDA + quad * 8);
#pragma unroll
        for (int mi = 0; mi < 4; mi++)
#pragma unroll
            for (int ni = 0; ni < 2; ni++)
                acc[mi][ni] = __builtin_amdgcn_mfma_f32_16x16x32_bf16(af[mi], bf[ni], acc[mi][ni], 0, 0, 0);
        __syncthreads();
    }

#pragma unroll
    for (int mi = 0; mi < 4; mi++) {
        int mbase = wm * 64 + mi * 16 + quad * 4;
#pragma unroll
        for (int r = 0; r < 4; r++) {
            int gr = m0 + mbase + r;
            if (gr >= cnt) continue;
            int t = list[e * NTOK + gr];
#pragma unroll
            for (int ni = 0; ni < 2; ni++) {
                int n = wn * 32 + ni * 16 + row16;
                unsafeAtomicAdd(&y[(size_t)t * DD + n0 + n], acc[mi][ni][r]);
            }
        }
    }
}

extern "C" void kernel_launch(void* const* d_in, const int* in_sizes, int n_in,
                              void* d_out, int out_size, void* d_ws, size_t ws_size,
                              hipStream_t stream)
{
    const float* x    = (const float*)d_in[0];
    const float* gw   = (const float*)d_in[1];
    const float* bias = (const float*)d_in[2];
    const float* wg   = (const float*)d_in[3];
    const float* wu   = (const float*)d_in[4];
    const float* wd   = (const float*)d_in[5];
    const float* sgw  = (const float*)d_in[6];
    const float* suw  = (const float*)d_in[7];
    const float* sdw  = (const float*)d_in[8];
    float* y = (float*)d_out;

    char* ws = (char*)d_ws;
    unsigned short* xbf  = (unsigned short*)(ws + OFF_XBF);
    unsigned short* hbuf = (unsigned short*)(ws + OFF_H);
    unsigned short* wgb  = (unsigned short*)(ws + OFF_WG);
    unsigned short* wub  = (unsigned short*)(ws + OFF_WU);
    unsigned short* wdb  = (unsigned short*)(ws + OFF_WD);
    int*   list     = (int*)(ws + OFF_LIST);
    float* scalebuf = (float*)(ws + OFF_SCALE);
    int*   count    = (int*)(ws + OFF_CNT);

    bool big = (ws_size >= WS_NEED);
    if (!big) {
        list     = (int*)(ws + 36ull * MB);
        scalebuf = (float*)(ws + 36ull * MB + 4ull * NEXP * NTOK);
        count    = (int*)(ws + 36ull * MB + 8ull * NEXP * NTOK);
    }

    // routing scratch aliased into hbuf region (consumed before gateup writes hbuf)
    unsigned int* emask = (unsigned int*)(ws + OFF_H);
    float*        tsc   = (float*)(ws + OFF_H + 4096);

    hipMemsetAsync(d_out, 0, (size_t)NTOK * DD * sizeof(float), stream);

    prep_kernel<<<dim3(NTOK * DD / 4 / 256), 256, 0, stream>>>(x, xbf, list, scalebuf, count);
    route_score_kernel<<<dim3(NTOK / 4), 256, 0, stream>>>(x, gw, bias, emask, tsc);
    build_lists_kernel<<<dim3(NE), 1024, 0, stream>>>(emask, tsc, count, list, scalebuf);

    if (big) {
        wconv_kernel<<<dim3((unsigned)((size_t)NEXP * II * DD / 4 / 2048), 3), 256, 0, stream>>>(
            wg, wu, wd, sgw, suw, sdw, wgb, wub, wdb);
        gateup_kernel<<<dim3(NEXP * 8 * 8), 256, 0, stream>>>(
            xbf, wgb, wub, count, list, scalebuf, hbuf);
        down_kernel<<<dim3(NEXP * 8 * 8), 256, 0, stream>>>(
            hbuf, wdb, count, list, y);
    } else {
        gateup_fb<<<dim3(NTOK / BM, II / BN, NEXP), 256, 0, stream>>>(
            xbf, wg, wu, sgw, suw, count, list, scalebuf, hbuf);
        down_fb<<<dim3(NTOK / BM, DD / BN, NEXP), 256, 0, stream>>>(
            hbuf, wd, sdw, count, list, y);
    }
}

// Round 5
// 432.092 us; speedup vs baseline: 1.1466x; 1.1466x over previous
//
#include <hip/hip_runtime.h>
#include <hip/hip_bf16.h>

// ---------------------------------------------------------------------------
// AfmoE MoE: routing (sigmoid top-8) + 16 routed SwiGLU experts + shared
// expert as expert #16 via gather lists.
// Round 7: atomic-free two-phase routing (was 112us of serialized atomics).
// Round 8: 128x128 tile BK=64 GEMMs + LDS quad-swizzle (87->79us gateup).
// Round 9: REGRESSION. launch_bounds(256,3)/(256,4) forced VGPR 104->84 and
//   spilled the 128-reg dual accumulator to scratch (WRITE_SIZE 18MB->156MB,
//   gateup 79->178us). Lesson: occupancy is REGISTER-limited here.
// Round 10 (this round):
//   - gateup restructured: single 128x128 GEMM with interleaved B-tile
//     (16-row blocks alternate Wg/Wu over the same 64 h-cols). acc 128->64
//     regs (m97 footprint), silu-mul pairs within-thread, 2 staging streams,
//     no forced min-waves -> no spill, natural ~3 waves/SIMD.
//   - down reverted to its proven (256,3).
//   - wconv keeps the 8x float4 ILP form.
// ---------------------------------------------------------------------------

typedef __attribute__((ext_vector_type(8))) short bf16x8;
typedef __attribute__((ext_vector_type(4))) float f32x4;

#define NTOK 1024   // B*S
#define DD   1024   // hidden
#define II   1024   // intermediate (same for shared)
#define NE   16     // routed experts
#define NEXP 17     // + shared expert as index 16
#define KSEL 8
#define RSCALE 2.826f

// fallback-path tiling
#define BM 128
#define BN 64
#define BK 32
#define LDA 40

// workspace layout (bytes)
#define MB (1024ull*1024ull)
#define OFF_XBF   0ull                         // ushort[NTOK*DD]          2 MiB
#define OFF_H     (2ull*MB)                    // ushort[NEXP*NTOK*II]    34 MiB
#define OFF_WG    (36ull*MB)                   // ushort[NEXP*II*DD]      34 MiB
#define OFF_WU    (70ull*MB)                   // ushort[NEXP*II*DD]      34 MiB
#define OFF_WD    (104ull*MB)                  // ushort[NEXP*DD*II]      34 MiB
#define OFF_LIST  (138ull*MB)                  // int[NEXP*NTOK]
#define OFF_SCALE (OFF_LIST + 4ull*NEXP*NTOK)  // float[NEXP*NTOK]
#define OFF_CNT   (OFF_SCALE + 4ull*NEXP*NTOK) // int[NEXP]
#define WS_NEED   (OFF_CNT + 4096ull)
// routing scratch aliased into the hbuf region (dead before gateup writes it):
//   emask: uint[NTOK] at OFF_H, tsc: float[NTOK*NE] at OFF_H+4096

__device__ __forceinline__ unsigned short f2bf(float f) {
    union { __hip_bfloat16 h; unsigned short u; } c;
    c.h = __float2bfloat16(f);
    return c.u;
}

__device__ __forceinline__ void gl2lds16(const unsigned short* g, unsigned short* l) {
    __builtin_amdgcn_global_load_lds(
        (const __attribute__((address_space(1))) void*)g,
        (__attribute__((address_space(3))) void*)l, 16, 0, 0);
}

// --- convert x to bf16; init shared-expert list/scale/count -----------------
__global__ __launch_bounds__(256) void prep_kernel(
    const float* __restrict__ x, unsigned short* __restrict__ xbf,
    int* __restrict__ list, float* __restrict__ scalebuf, int* __restrict__ count)
{
    int idx = blockIdx.x * 256 + threadIdx.x;
    float4 v = ((const float4*)x)[idx];
    ((ushort4*)xbf)[idx] = make_ushort4(f2bf(v.x), f2bf(v.y), f2bf(v.z), f2bf(v.w));
    if (idx < NTOK) { list[NE * NTOK + idx] = idx; scalebuf[NE * NTOK + idx] = 1.0f; }
    if (idx == 0) count[NE] = NTOK;
}

// --- convert all expert weights fp32 -> bf16 pools -------------------------
// 8 independent coalesced float4 loads per thread (ILP): idx = base + c*256 + tid
__global__ __launch_bounds__(256) void wconv_kernel(
    const float* __restrict__ wg, const float* __restrict__ wu, const float* __restrict__ wd,
    const float* __restrict__ sgw, const float* __restrict__ suw, const float* __restrict__ sdw,
    unsigned short* __restrict__ wgb, unsigned short* __restrict__ wub,
    unsigned short* __restrict__ wdb)
{
    const size_t ROUTED4 = (size_t)NE * II * DD / 4;
    int p = blockIdx.y;
    const float* rsrc = (p == 0) ? wg : (p == 1) ? wu : wd;
    const float* ssrc = (p == 0) ? sgw : (p == 1) ? suw : sdw;
    unsigned short* dst = (p == 0) ? wgb : (p == 1) ? wub : wdb;

    size_t base = (size_t)blockIdx.x * 2048 + threadIdx.x;
    float4 v[8];
#pragma unroll
    for (int c = 0; c < 8; c++) {
        size_t i4 = base + c * 256;
        const float* src = (i4 < ROUTED4) ? rsrc + 4 * i4 : ssrc + 4 * (i4 - ROUTED4);
        v[c] = *(const float4*)src;
    }
#pragma unroll
    for (int c = 0; c < 8; c++) {
        size_t i4 = base + c * 256;
        ((ushort4*)dst)[i4] = make_ushort4(f2bf(v[c].x), f2bf(v[c].y), f2bf(v[c].z), f2bf(v[c].w));
    }
}

// --- routing phase 1: scores + top-8 -> bitmask + scales (no atomics) ------
__global__ __launch_bounds__(256) void route_score_kernel(
    const float* __restrict__ x, const float* __restrict__ gw,
    const float* __restrict__ bias,
    unsigned int* __restrict__ emask, float* __restrict__ tsc)
{
    int wave = threadIdx.x >> 6, lane = threadIdx.x & 63;
    int t = blockIdx.x * 4 + wave;

    const float4* xr = (const float4*)(x + (size_t)t * DD);
    float acc[NE];
#pragma unroll
    for (int e = 0; e < NE; e++) acc[e] = 0.f;
#pragma unroll
    for (int i = 0; i < DD / 64 / 4; i++) {
        float4 xv = xr[lane + 64 * i];
#pragma unroll
        for (int e = 0; e < NE; e++) {
            float4 w = ((const float4*)(gw + (size_t)e * DD))[lane + 64 * i];
            acc[e] += xv.x * w.x + xv.y * w.y + xv.z * w.z + xv.w * w.w;
        }
    }
#pragma unroll
    for (int e = 0; e < NE; e++) {
        float v = acc[e];
        for (int off = 32; off > 0; off >>= 1) v += __shfl_xor(v, off, 64);
        acc[e] = v;
    }
    if (lane == 0) {
        float sc[NE], sel[NE];
#pragma unroll
        for (int e = 0; e < NE; e++) {
            sc[e] = 1.f / (1.f + expf(-acc[e]));
            sel[e] = sc[e] + bias[e];
        }
        bool used[NE] = {};
        int inds[KSEL];
        float ssum = 0.f;
        for (int k = 0; k < KSEL; k++) {
            float best = -1e30f; int bi = 0;
            for (int e = 0; e < NE; e++)
                if (!used[e] && sel[e] > best) { best = sel[e]; bi = e; }
            used[bi] = true; inds[k] = bi; ssum += sc[bi];
        }
        float inv = RSCALE / ssum;
        unsigned int m = 0;
        for (int k = 0; k < KSEL; k++) {
            int e = inds[k];
            m |= (1u << e);
            tsc[(size_t)t * NE + e] = sc[e] * inv;
        }
        emask[t] = m;
    }
}

// --- routing phase 2: per-expert gather lists via ballot prefix-scan -------
__global__ __launch_bounds__(1024) void build_lists_kernel(
    const unsigned int* __restrict__ emask, const float* __restrict__ tsc,
    int* __restrict__ count, int* __restrict__ list, float* __restrict__ scalebuf)
{
    int e = blockIdx.x;
    int t = threadIdx.x;
    int lane = t & 63, wave = t >> 6;
    bool sel = (emask[t] >> e) & 1u;
    unsigned long long m = __ballot(sel);
    int posw = __popcll(m & ((1ull << lane) - 1ull));
    int wtot = __popcll(m);
    __shared__ int woff[16];
    if (lane == 0) woff[wave] = wtot;
    __syncthreads();
    if (t == 0) {
        int s = 0;
#pragma unroll
        for (int w = 0; w < 16; w++) { int v = woff[w]; woff[w] = s; s += v; }
        count[e] = s;
    }
    __syncthreads();
    if (sel) {
        int pos = woff[wave] + posw;
        list[e * NTOK + pos] = t;
        scalebuf[e * NTOK + pos] = tsc[(size_t)t * NE + e];
    }
}

// --- fused gate+up GEMM: 128x128 tile, interleaved B (Wg/Wu), BK=64 --------
// grid 2176 = 17 experts x 16 n-tiles (64 h-cols) x 8 m-tiles, XCD-swizzled:
// all 8 m-tiles of one (e,n0) on one XCD (g%8==xcd) for L2 weight reuse.
// B LDS rows r: mat=(r>>4)&1 (0=Wg,1=Wu), src row = n0+(r>>5)*16+(r&15).
// acc[mi][ni]: ni even = G, ni odd = U, same h-col -> silu pair in-thread.
// Single 4x4 acc (64 regs) => no spill, natural ~3 waves/SIMD.
__global__ __launch_bounds__(256) void gateup_kernel(
    const unsigned short* __restrict__ xbf,
    const unsigned short* __restrict__ wgb, const unsigned short* __restrict__ wub,
    const int* __restrict__ count, const int* __restrict__ list,
    const float* __restrict__ scalebuf, unsigned short* __restrict__ hbuf)
{
    int s = blockIdx.x;
    int xcd = s & 7, t = s >> 3;
    int g = xcd + 8 * (t >> 3);          // (e,n0) group in [0,272), g%8==xcd
    int e = g >> 4;
    int n0 = (g & 15) * 64;
    int m0 = (t & 7) * 128;
    int cnt = count[e];
    if (m0 >= cnt) return;
    const unsigned short* Bg = wgb + (size_t)e * II * DD;
    const unsigned short* Bu = wub + (size_t)e * II * DD;

    __shared__ __align__(16) unsigned short As[8192];
    __shared__ __align__(16) unsigned short Bs[8192];
    __shared__ int rowtok[128];

    int tid = threadIdx.x;
    if (tid < 128) {
        int gr = m0 + tid;
        rowtok[tid] = list[e * NTOK + ((gr < cnt) ? gr : (cnt - 1))];
    }
    __syncthreads();

    int lane = tid & 63, wave = tid >> 6;
    int wm = wave & 1, wn = wave >> 1;
    int row16 = lane & 15, quad = lane >> 4;

    // staging: wave q-half = wave>>1; rows (wave&1)*64 + c*16 + (lane>>2)
    int qS = wave >> 1;
    int srow = (wave & 1) * 64 + (lane >> 2);
    int colS = ((lane & 3) ^ ((lane >> 3) & 3)) * 8;   // pre-swizzled source chunk
    int tokr[4];
#pragma unroll
    for (int c = 0; c < 4; c++) tokr[c] = rowtok[srow + c * 16];
    const unsigned short* gBsrc[4];
#pragma unroll
    for (int c = 0; c < 4; c++) {
        int cb = (wave & 1) * 4 + c;           // 16-row block index [0,8)
        const unsigned short* W = (cb & 1) ? Bu : Bg;
        gBsrc[c] = W + (size_t)(n0 + (cb >> 1) * 16 + (lane >> 2)) * DD + colS;
    }

    f32x4 acc[4][4];
#pragma unroll
    for (int mi = 0; mi < 4; mi++)
#pragma unroll
        for (int ni = 0; ni < 4; ni++) acc[mi][ni] = (f32x4){0.f, 0.f, 0.f, 0.f};

    int qe = (quad ^ ((row16 >> 1) & 3)) * 8;          // swizzled read chunk

    for (int k0 = 0; k0 < DD; k0 += 64) {
        int koff = k0 + qS * 32;
#pragma unroll
        for (int c = 0; c < 4; c++) {
            gl2lds16(xbf + (size_t)tokr[c] * DD + koff + colS, As + wave * 2048 + c * 512);
            gl2lds16(gBsrc[c] + koff, Bs + wave * 2048 + c * 512);
        }
        __syncthreads();

#pragma unroll
        for (int kk = 0; kk < 2; kk++) {
            bf16x8 a[4], b[4];
            int base = kk * 4096 + qe;
#pragma unroll
            for (int mi = 0; mi < 4; mi++)
                a[mi] = *(const bf16x8*)(As + base + (wm * 64 + mi * 16 + row16) * 32);
#pragma unroll
            for (int ni = 0; ni < 4; ni++)
                b[ni] = *(const bf16x8*)(Bs + base + (wn * 64 + ni * 16 + row16) * 32);
#pragma unroll
            for (int mi = 0; mi < 4; mi++)
#pragma unroll
                for (int ni = 0; ni < 4; ni++)
                    acc[mi][ni] = __builtin_amdgcn_mfma_f32_16x16x32_bf16(a[mi], b[ni], acc[mi][ni], 0, 0, 0);
        }
        __syncthreads();
    }

    // epilogue: acc pairs (G=ni even, U=ni odd) -> silu(g)*u*scale -> bf16 h
#pragma unroll
    for (int mi = 0; mi < 4; mi++) {
        int grb = m0 + wm * 64 + mi * 16 + quad * 4;
#pragma unroll
        for (int r = 0; r < 4; r++) {
            int gr = grb + r;
            if (gr >= cnt) continue;
            float rs = scalebuf[e * NTOK + gr];
            size_t rowoff = ((size_t)e * NTOK + gr) * II + n0 + wn * 32;
#pragma unroll
            for (int j = 0; j < 2; j++) {
                float g2 = acc[mi][2 * j][r], u = acc[mi][2 * j + 1][r];
                float h = g2 / (1.f + __expf(-g2)) * u * rs;
                hbuf[rowoff + j * 16 + row16] = f2bf(h);
            }
        }
    }
}

// --- down GEMM: BM=128 BN=128 BK=64, XCD-swizzled; atomic scatter into y ---
__global__ __launch_bounds__(256, 3) void down_kernel(
    const unsigned short* __restrict__ hbuf,
    const unsigned short* __restrict__ wdb,
    const int* __restrict__ count, const int* __restrict__ list,
    float* __restrict__ y)
{
    int s = blockIdx.x;
    int xcd = s & 7, t = s >> 3;
    int g = xcd + 8 * (t >> 3);
    int e = g >> 3;
    int n0 = (g & 7) * 128;
    int m0 = (t & 7) * 128;
    int cnt = count[e];
    if (m0 >= cnt) return;
    const unsigned short* Bp = wdb + (size_t)e * DD * II;

    __shared__ __align__(16) unsigned short As[8192];
    __shared__ __align__(16) unsigned short Bs[8192];

    int tid = threadIdx.x;
    int lane = tid & 63, wave = tid >> 6;
    int wm = wave & 1, wn = wave >> 1;
    int row16 = lane & 15, quad = lane >> 4;

    int qS = wave >> 1;
    int srow = (wave & 1) * 64 + (lane >> 2);
    int colS = ((lane & 3) ^ ((lane >> 3) & 3)) * 8;

    size_t arow[4];
#pragma unroll
    for (int c = 0; c < 4; c++) {
        int gr = m0 + srow + c * 16;
        int idx = (gr < cnt) ? gr : (cnt - 1);   // clamp: garbage rows skipped in epilogue
        arow[c] = ((size_t)e * NTOK + idx) * II;
    }
    const unsigned short* gB0 = Bp + (size_t)(n0 + srow) * II + colS;

    f32x4 acc[4][4];
#pragma unroll
    for (int mi = 0; mi < 4; mi++)
#pragma unroll
        for (int ni = 0; ni < 4; ni++) acc[mi][ni] = (f32x4){0.f, 0.f, 0.f, 0.f};

    int qe = (quad ^ ((row16 >> 1) & 3)) * 8;

    for (int k0 = 0; k0 < II; k0 += 64) {
        int koff = k0 + qS * 32;
#pragma unroll
        for (int c = 0; c < 4; c++) {
            gl2lds16(hbuf + arow[c] + koff + colS, As + wave * 2048 + c * 512);
            gl2lds16(gB0 + (size_t)(c * 16) * II + koff, Bs + wave * 2048 + c * 512);
        }
        __syncthreads();

#pragma unroll
        for (int kk = 0; kk < 2; kk++) {
            bf16x8 a[4], b[4];
            int base = kk * 4096 + qe;
#pragma unroll
            for (int mi = 0; mi < 4; mi++)
                a[mi] = *(const bf16x8*)(As + base + (wm * 64 + mi * 16 + row16) * 32);
#pragma unroll
            for (int ni = 0; ni < 4; ni++)
                b[ni] = *(const bf16x8*)(Bs + base + (wn * 64 + ni * 16 + row16) * 32);
#pragma unroll
            for (int mi = 0; mi < 4; mi++)
#pragma unroll
                for (int ni = 0; ni < 4; ni++)
                    acc[mi][ni] = __builtin_amdgcn_mfma_f32_16x16x32_bf16(a[mi], b[ni], acc[mi][ni], 0, 0, 0);
        }
        __syncthreads();
    }

#pragma unroll
    for (int mi = 0; mi < 4; mi++) {
        int grb = m0 + wm * 64 + mi * 16 + quad * 4;
#pragma unroll
        for (int r = 0; r < 4; r++) {
            int gr = grb + r;
            if (gr >= cnt) continue;
            int tk = list[e * NTOK + gr];
            float* yr = y + (size_t)tk * DD + n0 + wn * 64;
#pragma unroll
            for (int ni = 0; ni < 4; ni++)
                unsafeAtomicAdd(yr + ni * 16 + row16, acc[mi][ni][r]);
        }
    }
}

// ======================= fallback path (round-0 kernels) ====================
__global__ __launch_bounds__(256) void gateup_fb(
    const unsigned short* __restrict__ xbf,
    const float* __restrict__ wg, const float* __restrict__ wu,
    const float* __restrict__ sgw, const float* __restrict__ suw,
    const int* __restrict__ count, const int* __restrict__ list,
    const float* __restrict__ scalebuf, unsigned short* __restrict__ hbuf)
{
    int e = blockIdx.z;
    int cnt = count[e];
    int m0 = blockIdx.x * BM;
    if (m0 >= cnt) return;
    int n0 = blockIdx.y * BN;
    const float* Bg = (e < NE) ? wg + (size_t)e * II * DD : sgw;
    const float* Bu = (e < NE) ? wu + (size_t)e * II * DD : suw;

    __shared__ __align__(16) unsigned short As[BM * LDA];
    __shared__ __align__(16) unsigned short Bgs[BN * LDA];
    __shared__ __align__(16) unsigned short Bus[BN * LDA];
    __shared__ int rowtok[BM];

    int tid = threadIdx.x;
    if (tid < BM) {
        int gr = m0 + tid;
        rowtok[tid] = (gr < cnt) ? list[e * NTOK + gr] : -1;
    }
    __syncthreads();

    int lane = tid & 63, wave = tid >> 6;
    int wm = wave >> 1, wn = wave & 1;
    int row16 = lane & 15, quad = lane >> 4;

    f32x4 accG[4][2], accU[4][2];
#pragma unroll
    for (int mi = 0; mi < 4; mi++)
#pragma unroll
        for (int ni = 0; ni < 2; ni++) {
            accG[mi][ni] = (f32x4){0.f, 0.f, 0.f, 0.f};
            accU[mi][ni] = (f32x4){0.f, 0.f, 0.f, 0.f};
        }

    for (int k0 = 0; k0 < DD; k0 += BK) {
#pragma unroll
        for (int i = 0; i < 2; i++) {
            int c = tid + 256 * i;
            int row = c >> 2, kc = (c & 3) * 8;
            int tok = rowtok[row];
            uint4 v = (tok >= 0) ? *(const uint4*)(xbf + (size_t)tok * DD + k0 + kc)
                                 : make_uint4(0u, 0u, 0u, 0u);
            *(uint4*)(As + row * LDA + kc) = v;
        }
#pragma unroll
        for (int i = 0; i < 2; i++) {
            int c = tid + 256 * i;
            int row = c >> 3, f = (c & 7) * 4;
            float4 vg = *(const float4*)(Bg + (size_t)(n0 + row) * DD + k0 + f);
            float4 vu = *(const float4*)(Bu + (size_t)(n0 + row) * DD + k0 + f);
            *(ushort4*)(Bgs + row * LDA + f) = make_ushort4(f2bf(vg.x), f2bf(vg.y), f2bf(vg.z), f2bf(vg.w));
            *(ushort4*)(Bus + row * LDA + f) = make_ushort4(f2bf(vu.x), f2bf(vu.y), f2bf(vu.z), f2bf(vu.w));
        }
        __syncthreads();

        bf16x8 af[4], bg[2], bu[2];
#pragma unroll
        for (int mi = 0; mi < 4; mi++)
            af[mi] = *(const bf16x8*)(As + (wm * 64 + mi * 16 + row16) * LDA + quad * 8);
#pragma unroll
        for (int ni = 0; ni < 2; ni++) {
            bg[ni] = *(const bf16x8*)(Bgs + (wn * 32 + ni * 16 + row16) * LDA + quad * 8);
            bu[ni] = *(const bf16x8*)(Bus + (wn * 32 + ni * 16 + row16) * LDA + quad * 8);
        }
#pragma unroll
        for (int mi = 0; mi < 4; mi++)
#pragma unroll
            for (int ni = 0; ni < 2; ni++) {
                accG[mi][ni] = __builtin_amdgcn_mfma_f32_16x16x32_bf16(af[mi], bg[ni], accG[mi][ni], 0, 0, 0);
                accU[mi][ni] = __builtin_amdgcn_mfma_f32_16x16x32_bf16(af[mi], bu[ni], accU[mi][ni], 0, 0, 0);
            }
        __syncthreads();
    }

#pragma unroll
    for (int mi = 0; mi < 4; mi++) {
        int mbase = wm * 64 + mi * 16 + quad * 4;
#pragma unroll
        for (int r = 0; r < 4; r++) {
            int gr = m0 + mbase + r;
            if (gr >= cnt) continue;
            float rs = scalebuf[e * NTOK + gr];
            size_t rowoff = ((size_t)e * NTOK + gr) * II + n0;
#pragma unroll
            for (int ni = 0; ni < 2; ni++) {
                int n = wn * 32 + ni * 16 + row16;
                float g = accG[mi][ni][r], u = accU[mi][ni][r];
                float h = g / (1.f + __expf(-g)) * u * rs;
                hbuf[rowoff + n] = f2bf(h);
            }
        }
    }
}

__global__ __launch_bounds__(256) void down_fb(
    const unsigned short* __restrict__ hbuf,
    const float* __restrict__ wd, const float* __restrict__ sdw,
    const int* __restrict__ count, const int* __restrict__ list,
    float* __restrict__ y)
{
    int e = blockIdx.z;
    int cnt = count[e];
    int m0 = blockIdx.x * BM;
    if (m0 >= cnt) return;
    int n0 = blockIdx.y * BN;
    const float* Bp = (e < NE) ? wd + (size_t)e * DD * II : sdw;

    __shared__ __align__(16) unsigned short As[BM * LDA];
    __shared__ __align__(16) unsigned short Bs[BN * LDA];

    int tid = threadIdx.x;
    int lane = tid & 63, wave = tid >> 6;
    int wm = wave >> 1, wn = wave & 1;
    int row16 = lane & 15, quad = lane >> 4;

    f32x4 acc[4][2];
#pragma unroll
    for (int mi = 0; mi < 4; mi++)
#pragma unroll
        for (int ni = 0; ni < 2; ni++) acc[mi][ni] = (f32x4){0.f, 0.f, 0.f, 0.f};

    const unsigned short* Abase = hbuf + ((size_t)e * NTOK + m0) * II;

    for (int k0 = 0; k0 < II; k0 += BK) {
#pragma unroll
        for (int i = 0; i < 2; i++) {
            int c = tid + 256 * i;
            int row = c >> 2, kc = (c & 3) * 8;
            uint4 v = (m0 + row < cnt) ? *(const uint4*)(Abase + (size_t)row * II + k0 + kc)
                                       : make_uint4(0u, 0u, 0u, 0u);
            *(uint4*)(As + row * LDA + kc) = v;
        }
#pragma unroll
        for (int i = 0; i < 2; i++) {
            int c = tid + 256 * i;
            int row = c >> 3, f = (c & 7) * 4;
            float4 v = *(const float4*)(Bp + (size_t)(n0 + row) * II + k0 + f);
            *(ushort4*)(Bs + row * LDA + f) = make_ushort4(f2bf(v.x), f2bf(v.y), f2bf(v.z), f2bf(v.w));
        }
        __syncthreads();

        bf16x8 af[4], bf[2];
#pragma unroll
        for (int mi = 0; mi < 4; mi++)
            af[mi] = *(const bf16x8*)(As + (wm * 64 + mi * 16 + row16) * LDA + quad * 8);
#pragma unroll
        for (int ni = 0; ni < 2; ni++)
            bf[ni] = *(const bf16x8*)(Bs + (wn * 32 + ni * 16 + row16) * LDA + quad * 8);
#pragma unroll
        for (int mi = 0; mi < 4; mi++)
#pragma unroll
            for (int ni = 0; ni < 2; ni++)
                acc[mi][ni] = __builtin_amdgcn_mfma_f32_16x16x32_bf16(af[mi], bf[ni], acc[mi][ni], 0, 0, 0);
        __syncthreads();
    }

#pragma unroll
    for (int mi = 0; mi < 4; mi++) {
        int mbase = wm * 64 + mi * 16 + quad * 4;
#pragma unroll
        for (int r = 0; r < 4; r++) {
            int gr = m0 + mbase + r;
            if (gr >= cnt) continue;
            int t = list[e * NTOK + gr];
#pragma unroll
            for (int ni = 0; ni < 2; ni++) {
                int n = wn * 32 + ni * 16 + row16;
                unsafeAtomicAdd(&y[(size_t)t * DD + n0 + n], acc[mi][ni][r]);
            }
        }
    }
}

extern "C" void kernel_launch(void* const* d_in, const int* in_sizes, int n_in,
                              void* d_out, int out_size, void* d_ws, size_t ws_size,
                              hipStream_t stream)
{
    const float* x    = (const float*)d_in[0];
    const float* gw   = (const float*)d_in[1];
    const float* bias = (const float*)d_in[2];
    const float* wg   = (const float*)d_in[3];
    const float* wu   = (const float*)d_in[4];
    const float* wd   = (const float*)d_in[5];
    const float* sgw  = (const float*)d_in[6];
    const float* suw  = (const float*)d_in[7];
    const float* sdw  = (const float*)d_in[8];
    float* y = (float*)d_out;

    char* ws = (char*)d_ws;
    unsigned short* xbf  = (unsigned short*)(ws + OFF_XBF);
    unsigned short* hbuf = (unsigned short*)(ws + OFF_H);
    unsigned short* wgb  = (unsigned short*)(ws + OFF_WG);
    unsigned short* wub  = (unsigned short*)(ws + OFF_WU);
    unsigned short* wdb  = (unsigned short*)(ws + OFF_WD);
    int*   list     = (int*)(ws + OFF_LIST);
    float* scalebuf = (float*)(ws + OFF_SCALE);
    int*   count    = (int*)(ws + OFF_CNT);

    bool big = (ws_size >= WS_NEED);
    if (!big) {
        list     = (int*)(ws + 36ull * MB);
        scalebuf = (float*)(ws + 36ull * MB + 4ull * NEXP * NTOK);
        count    = (int*)(ws + 36ull * MB + 8ull * NEXP * NTOK);
    }

    // routing scratch aliased into hbuf region (consumed before gateup writes hbuf)
    unsigned int* emask = (unsigned int*)(ws + OFF_H);
    float*        tsc   = (float*)(ws + OFF_H + 4096);

    hipMemsetAsync(d_out, 0, (size_t)NTOK * DD * sizeof(float), stream);

    prep_kernel<<<dim3(NTOK * DD / 4 / 256), 256, 0, stream>>>(x, xbf, list, scalebuf, count);
    route_score_kernel<<<dim3(NTOK / 4), 256, 0, stream>>>(x, gw, bias, emask, tsc);
    build_lists_kernel<<<dim3(NE), 1024, 0, stream>>>(emask, tsc, count, list, scalebuf);

    if (big) {
        wconv_kernel<<<dim3((unsigned)((size_t)NEXP * II * DD / 4 / 2048), 3), 256, 0, stream>>>(
            wg, wu, wd, sgw, suw, sdw, wgb, wub, wdb);
        gateup_kernel<<<dim3(NEXP * 16 * 8), 256, 0, stream>>>(
            xbf, wgb, wub, count, list, scalebuf, hbuf);
        down_kernel<<<dim3(NEXP * 8 * 8), 256, 0, stream>>>(
            hbuf, wdb, count, list, y);
    } else {
        gateup_fb<<<dim3(NTOK / BM, II / BN, NEXP), 256, 0, stream>>>(
            xbf, wg, wu, sgw, suw, count, list, scalebuf, hbuf);
        down_fb<<<dim3(NTOK / BM, DD / BN, NEXP), 256, 0, stream>>>(
            hbuf, wd, sdw, count, list, y);
    }
}

// Round 6
// 393.924 us; speedup vs baseline: 1.2577x; 1.0969x over previous
//
#include <hip/hip_runtime.h>
#include <hip/hip_bf16.h>

// ---------------------------------------------------------------------------
// AfmoE MoE: routing (sigmoid top-8) + 16 routed SwiGLU experts + shared
// expert as expert #16 via gather lists.
// Round 7: atomic-free two-phase routing (was 112us of serialized atomics).
// Round 8: 128x128 tile BK=64 GEMMs + LDS quad-swizzle -> gateup 79us.
// Round 9: REGRESSION (forced min-waves spilled 128-reg dual acc).
// Round 10: REGRESSION (interleaved-B halves A-reuse: 87->65 FLOP/B, 2x
//   barriers/MFMA; 79->108us). Lesson: dual-acc @ (256,2) IS the optimum.
// Round 11 (this round):
//   - gateup reverted verbatim to the round-8 (78.9us measured) kernel.
//   - down atomics replaced (tier-gated on ws_size): down_pb stores partial
//     rows (plain f32, compacted 9216-row buffer) + combine_kernel sums 9
//     partials per token via poslut. Removes 9.4M 4-byte L2 atomic RMWs.
//   - count memset removed (build_lists writes counts unconditionally);
//     y memset skipped in pb tier (combine overwrites).
// ---------------------------------------------------------------------------

typedef __attribute__((ext_vector_type(8))) short bf16x8;
typedef __attribute__((ext_vector_type(4))) float f32x4;

#define NTOK 1024   // B*S
#define DD   1024   // hidden
#define II   1024   // intermediate (same for shared)
#define NE   16     // routed experts
#define NEXP 17     // + shared expert as index 16
#define KSEL 8
#define RSCALE 2.826f

// fallback-path tiling
#define BM 128
#define BN 64
#define BK 32
#define LDA 40

// workspace layout (bytes)
#define MB (1024ull*1024ull)
#define OFF_XBF   0ull                         // ushort[NTOK*DD]          2 MiB
#define OFF_H     (2ull*MB)                    // ushort[NEXP*NTOK*II]    34 MiB
#define OFF_WG    (36ull*MB)                   // ushort[NEXP*II*DD]      34 MiB
#define OFF_WU    (70ull*MB)                   // ushort[NEXP*II*DD]      34 MiB
#define OFF_WD    (104ull*MB)                  // ushort[NEXP*DD*II]      34 MiB
#define OFF_LIST  (138ull*MB)                  // int[NEXP*NTOK]
#define OFF_SCALE (OFF_LIST + 4ull*NEXP*NTOK)  // float[NEXP*NTOK]
#define OFF_CNT   (OFF_SCALE + 4ull*NEXP*NTOK) // int[NEXP] (+ pad)
#define WS_NEED   (OFF_CNT + 4096ull)
// tier-2 (partial-sum down, no atomics):
#define OFF_POS   WS_NEED                      // int[NE*NTOK] = 64 KiB
#define OFF_PBUF  (OFF_POS + 4ull*NE*NTOK)     // float[9216*DD] = 36 MiB
#define WS_NEED2  (OFF_PBUF + 4ull*9216*DD)
// routing scratch aliased into the hbuf region (dead before gateup writes it):
//   emask: uint[NTOK] at OFF_H, tsc: float[NTOK*NE] at OFF_H+4096

__device__ __forceinline__ unsigned short f2bf(float f) {
    union { __hip_bfloat16 h; unsigned short u; } c;
    c.h = __float2bfloat16(f);
    return c.u;
}

__device__ __forceinline__ void gl2lds16(const unsigned short* g, unsigned short* l) {
    __builtin_amdgcn_global_load_lds(
        (const __attribute__((address_space(1))) void*)g,
        (__attribute__((address_space(3))) void*)l, 16, 0, 0);
}

// --- convert x to bf16; init shared-expert list/scale/count -----------------
__global__ __launch_bounds__(256) void prep_kernel(
    const float* __restrict__ x, unsigned short* __restrict__ xbf,
    int* __restrict__ list, float* __restrict__ scalebuf, int* __restrict__ count)
{
    int idx = blockIdx.x * 256 + threadIdx.x;
    float4 v = ((const float4*)x)[idx];
    ((ushort4*)xbf)[idx] = make_ushort4(f2bf(v.x), f2bf(v.y), f2bf(v.z), f2bf(v.w));
    if (idx < NTOK) { list[NE * NTOK + idx] = idx; scalebuf[NE * NTOK + idx] = 1.0f; }
    if (idx == 0) count[NE] = NTOK;
}

// --- convert all expert weights fp32 -> bf16 pools (8x float4 ILP) ---------
__global__ __launch_bounds__(256) void wconv_kernel(
    const float* __restrict__ wg, const float* __restrict__ wu, const float* __restrict__ wd,
    const float* __restrict__ sgw, const float* __restrict__ suw, const float* __restrict__ sdw,
    unsigned short* __restrict__ wgb, unsigned short* __restrict__ wub,
    unsigned short* __restrict__ wdb)
{
    const size_t ROUTED4 = (size_t)NE * II * DD / 4;
    int p = blockIdx.y;
    const float* rsrc = (p == 0) ? wg : (p == 1) ? wu : wd;
    const float* ssrc = (p == 0) ? sgw : (p == 1) ? suw : sdw;
    unsigned short* dst = (p == 0) ? wgb : (p == 1) ? wub : wdb;

    size_t base = (size_t)blockIdx.x * 2048 + threadIdx.x;
    float4 v[8];
#pragma unroll
    for (int c = 0; c < 8; c++) {
        size_t i4 = base + c * 256;
        const float* src = (i4 < ROUTED4) ? rsrc + 4 * i4 : ssrc + 4 * (i4 - ROUTED4);
        v[c] = *(const float4*)src;
    }
#pragma unroll
    for (int c = 0; c < 8; c++) {
        size_t i4 = base + c * 256;
        ((ushort4*)dst)[i4] = make_ushort4(f2bf(v[c].x), f2bf(v[c].y), f2bf(v[c].z), f2bf(v[c].w));
    }
}

// --- routing phase 1: scores + top-8 -> bitmask + scales (no atomics) ------
__global__ __launch_bounds__(256) void route_score_kernel(
    const float* __restrict__ x, const float* __restrict__ gw,
    const float* __restrict__ bias,
    unsigned int* __restrict__ emask, float* __restrict__ tsc)
{
    int wave = threadIdx.x >> 6, lane = threadIdx.x & 63;
    int t = blockIdx.x * 4 + wave;

    const float4* xr = (const float4*)(x + (size_t)t * DD);
    float acc[NE];
#pragma unroll
    for (int e = 0; e < NE; e++) acc[e] = 0.f;
#pragma unroll
    for (int i = 0; i < DD / 64 / 4; i++) {
        float4 xv = xr[lane + 64 * i];
#pragma unroll
        for (int e = 0; e < NE; e++) {
            float4 w = ((const float4*)(gw + (size_t)e * DD))[lane + 64 * i];
            acc[e] += xv.x * w.x + xv.y * w.y + xv.z * w.z + xv.w * w.w;
        }
    }
#pragma unroll
    for (int e = 0; e < NE; e++) {
        float v = acc[e];
        for (int off = 32; off > 0; off >>= 1) v += __shfl_xor(v, off, 64);
        acc[e] = v;
    }
    if (lane == 0) {
        float sc[NE], sel[NE];
#pragma unroll
        for (int e = 0; e < NE; e++) {
            sc[e] = 1.f / (1.f + expf(-acc[e]));
            sel[e] = sc[e] + bias[e];
        }
        bool used[NE] = {};
        int inds[KSEL];
        float ssum = 0.f;
        for (int k = 0; k < KSEL; k++) {
            float best = -1e30f; int bi = 0;
            for (int e = 0; e < NE; e++)
                if (!used[e] && sel[e] > best) { best = sel[e]; bi = e; }
            used[bi] = true; inds[k] = bi; ssum += sc[bi];
        }
        float inv = RSCALE / ssum;
        unsigned int m = 0;
        for (int k = 0; k < KSEL; k++) {
            int e = inds[k];
            m |= (1u << e);
            tsc[(size_t)t * NE + e] = sc[e] * inv;
        }
        emask[t] = m;
    }
}

// --- routing phase 2: per-expert gather lists via ballot prefix-scan -------
// Also writes poslut[e*NTOK+t] = position of t in e's list (or -1) when the
// tier-2 workspace is available (poslut != nullptr).
__global__ __launch_bounds__(1024) void build_lists_kernel(
    const unsigned int* __restrict__ emask, const float* __restrict__ tsc,
    int* __restrict__ count, int* __restrict__ list, float* __restrict__ scalebuf,
    int* __restrict__ poslut)
{
    int e = blockIdx.x;
    int t = threadIdx.x;
    int lane = t & 63, wave = t >> 6;
    bool sel = (emask[t] >> e) & 1u;
    unsigned long long m = __ballot(sel);
    int posw = __popcll(m & ((1ull << lane) - 1ull));
    int wtot = __popcll(m);
    __shared__ int woff[16];
    if (lane == 0) woff[wave] = wtot;
    __syncthreads();
    if (t == 0) {
        int s = 0;
#pragma unroll
        for (int w = 0; w < 16; w++) { int v = woff[w]; woff[w] = s; s += v; }
        count[e] = s;
    }
    __syncthreads();
    int pos = woff[wave] + posw;
    if (sel) {
        list[e * NTOK + pos] = t;
        scalebuf[e * NTOK + pos] = tsc[(size_t)t * NE + e];
    }
    if (poslut) poslut[e * NTOK + t] = sel ? pos : -1;
}

// --- fused gate+up GEMM: BM=128 BN=128 BK=64, XCD-swizzled 1-D grid --------
// (round-8 structure, 78.9us measured). grid 1088 = 17 experts x 8 n-tiles
// x 8 m-tiles; all 8 m-tiles of one (e,n0) on one XCD for L2 weight reuse.
// LDS: 3 x 16KB [q(2)][row(128)][32] buffers; quad-swizzle via pre-swizzled
// global source + swizzled ds_read (gl2lds dest linear).
__global__ __launch_bounds__(256, 2) void gateup_kernel(
    const unsigned short* __restrict__ xbf,
    const unsigned short* __restrict__ wgb, const unsigned short* __restrict__ wub,
    const int* __restrict__ count, const int* __restrict__ list,
    const float* __restrict__ scalebuf, unsigned short* __restrict__ hbuf)
{
    int s = blockIdx.x;
    int xcd = s & 7, t = s >> 3;
    int g = xcd + 8 * (t >> 3);          // (e,n0) group, g%8 == xcd
    int e = g >> 3;
    int n0 = (g & 7) * 128;
    int m0 = (t & 7) * 128;
    int cnt = count[e];
    if (m0 >= cnt) return;
    const unsigned short* Bg = wgb + (size_t)e * II * DD;
    const unsigned short* Bu = wub + (size_t)e * II * DD;

    __shared__ __align__(16) unsigned short As[8192];
    __shared__ __align__(16) unsigned short Bgs[8192];
    __shared__ __align__(16) unsigned short Bus[8192];
    __shared__ int rowtok[128];

    int tid = threadIdx.x;
    if (tid < 128) {
        int gr = m0 + tid;
        rowtok[tid] = list[e * NTOK + ((gr < cnt) ? gr : (cnt - 1))];
    }
    __syncthreads();

    int lane = tid & 63, wave = tid >> 6;
    int wm = wave & 1, wn = wave >> 1;
    int row16 = lane & 15, quad = lane >> 4;

    // staging geometry: wave covers q = wave>>1, rows (wave&1)*64 + c*16 + (lane>>2)
    int qS = wave >> 1;
    int srow = (wave & 1) * 64 + (lane >> 2);          // + c*16
    int colS = ((lane & 3) ^ ((lane >> 3) & 3)) * 8;   // pre-swizzled source chunk
    int tokr[4];
#pragma unroll
    for (int c = 0; c < 4; c++) tokr[c] = rowtok[srow + c * 16];
    const unsigned short* gBg0 = Bg + (size_t)(n0 + srow) * DD + colS;
    const unsigned short* gBu0 = Bu + (size_t)(n0 + srow) * DD + colS;

    f32x4 accG[4][4], accU[4][4];
#pragma unroll
    for (int mi = 0; mi < 4; mi++)
#pragma unroll
        for (int ni = 0; ni < 4; ni++) {
            accG[mi][ni] = (f32x4){0.f, 0.f, 0.f, 0.f};
            accU[mi][ni] = (f32x4){0.f, 0.f, 0.f, 0.f};
        }

    int qe = (quad ^ ((row16 >> 1) & 3)) * 8;          // swizzled read chunk

    for (int k0 = 0; k0 < DD; k0 += 64) {
        int koff = k0 + qS * 32;
#pragma unroll
        for (int c = 0; c < 4; c++) {
            gl2lds16(xbf + (size_t)tokr[c] * DD + koff + colS, As + wave * 2048 + c * 512);
            gl2lds16(gBg0 + (size_t)(c * 16) * DD + koff, Bgs + wave * 2048 + c * 512);
            gl2lds16(gBu0 + (size_t)(c * 16) * DD + koff, Bus + wave * 2048 + c * 512);
        }
        __syncthreads();

#pragma unroll
        for (int kk = 0; kk < 2; kk++) {
            bf16x8 a[4], bg[4], bu[4];
            int base = kk * 4096 + qe;
#pragma unroll
            for (int mi = 0; mi < 4; mi++)
                a[mi] = *(const bf16x8*)(As + base + (wm * 64 + mi * 16 + row16) * 32);
#pragma unroll
            for (int ni = 0; ni < 4; ni++) {
                bg[ni] = *(const bf16x8*)(Bgs + base + (wn * 64 + ni * 16 + row16) * 32);
                bu[ni] = *(const bf16x8*)(Bus + base + (wn * 64 + ni * 16 + row16) * 32);
            }
#pragma unroll
            for (int mi = 0; mi < 4; mi++)
#pragma unroll
                for (int ni = 0; ni < 4; ni++) {
                    accG[mi][ni] = __builtin_amdgcn_mfma_f32_16x16x32_bf16(a[mi], bg[ni], accG[mi][ni], 0, 0, 0);
                    accU[mi][ni] = __builtin_amdgcn_mfma_f32_16x16x32_bf16(a[mi], bu[ni], accU[mi][ni], 0, 0, 0);
                }
        }
        __syncthreads();
    }

    // epilogue: silu(g)*u * route_scale -> bf16 h
#pragma unroll
    for (int mi = 0; mi < 4; mi++) {
        int grb = m0 + wm * 64 + mi * 16 + quad * 4;
#pragma unroll
        for (int r = 0; r < 4; r++) {
            int gr = grb + r;
            if (gr >= cnt) continue;
            float rs = scalebuf[e * NTOK + gr];
            size_t rowoff = ((size_t)e * NTOK + gr) * II + n0 + wn * 64;
#pragma unroll
            for (int ni = 0; ni < 4; ni++) {
                float g2 = accG[mi][ni][r], u = accU[mi][ni][r];
                float h = g2 / (1.f + __expf(-g2)) * u * rs;
                hbuf[rowoff + ni * 16 + row16] = f2bf(h);
            }
        }
    }
}

// --- down GEMM common body via macro-free duplication ----------------------
// tier-1: atomic scatter into y.  tier-2: plain stores into compacted pbuf.
__global__ __launch_bounds__(256, 3) void down_kernel(
    const unsigned short* __restrict__ hbuf,
    const unsigned short* __restrict__ wdb,
    const int* __restrict__ count, const int* __restrict__ list,
    float* __restrict__ y)
{
    int s = blockIdx.x;
    int xcd = s & 7, t = s >> 3;
    int g = xcd + 8 * (t >> 3);
    int e = g >> 3;
    int n0 = (g & 7) * 128;
    int m0 = (t & 7) * 128;
    int cnt = count[e];
    if (m0 >= cnt) return;
    const unsigned short* Bp = wdb + (size_t)e * DD * II;

    __shared__ __align__(16) unsigned short As[8192];
    __shared__ __align__(16) unsigned short Bs[8192];

    int tid = threadIdx.x;
    int lane = tid & 63, wave = tid >> 6;
    int wm = wave & 1, wn = wave >> 1;
    int row16 = lane & 15, quad = lane >> 4;

    int qS = wave >> 1;
    int srow = (wave & 1) * 64 + (lane >> 2);
    int colS = ((lane & 3) ^ ((lane >> 3) & 3)) * 8;

    size_t arow[4];
#pragma unroll
    for (int c = 0; c < 4; c++) {
        int gr = m0 + srow + c * 16;
        int idx = (gr < cnt) ? gr : (cnt - 1);
        arow[c] = ((size_t)e * NTOK + idx) * II;
    }
    const unsigned short* gB0 = Bp + (size_t)(n0 + srow) * II + colS;

    f32x4 acc[4][4];
#pragma unroll
    for (int mi = 0; mi < 4; mi++)
#pragma unroll
        for (int ni = 0; ni < 4; ni++) acc[mi][ni] = (f32x4){0.f, 0.f, 0.f, 0.f};

    int qe = (quad ^ ((row16 >> 1) & 3)) * 8;

    for (int k0 = 0; k0 < II; k0 += 64) {
        int koff = k0 + qS * 32;
#pragma unroll
        for (int c = 0; c < 4; c++) {
            gl2lds16(hbuf + arow[c] + koff + colS, As + wave * 2048 + c * 512);
            gl2lds16(gB0 + (size_t)(c * 16) * II + koff, Bs + wave * 2048 + c * 512);
        }
        __syncthreads();

#pragma unroll
        for (int kk = 0; kk < 2; kk++) {
            bf16x8 a[4], b[4];
            int base = kk * 4096 + qe;
#pragma unroll
            for (int mi = 0; mi < 4; mi++)
                a[mi] = *(const bf16x8*)(As + base + (wm * 64 + mi * 16 + row16) * 32);
#pragma unroll
            for (int ni = 0; ni < 4; ni++)
                b[ni] = *(const bf16x8*)(Bs + base + (wn * 64 + ni * 16 + row16) * 32);
#pragma unroll
            for (int mi = 0; mi < 4; mi++)
#pragma unroll
                for (int ni = 0; ni < 4; ni++)
                    acc[mi][ni] = __builtin_amdgcn_mfma_f32_16x16x32_bf16(a[mi], b[ni], acc[mi][ni], 0, 0, 0);
        }
        __syncthreads();
    }

#pragma unroll
    for (int mi = 0; mi < 4; mi++) {
        int grb = m0 + wm * 64 + mi * 16 + quad * 4;
#pragma unroll
        for (int r = 0; r < 4; r++) {
            int gr = grb + r;
            if (gr >= cnt) continue;
            int tk = list[e * NTOK + gr];
            float* yr = y + (size_t)tk * DD + n0 + wn * 64;
#pragma unroll
            for (int ni = 0; ni < 4; ni++)
                unsafeAtomicAdd(yr + ni * 16 + row16, acc[mi][ni][r]);
        }
    }
}

// tier-2 down: identical GEMM, epilogue stores into pbuf[base[e]+gr] rows.
__global__ __launch_bounds__(256, 3) void down_pb_kernel(
    const unsigned short* __restrict__ hbuf,
    const unsigned short* __restrict__ wdb,
    const int* __restrict__ count, float* __restrict__ pbuf)
{
    int s = blockIdx.x;
    int xcd = s & 7, t = s >> 3;
    int g = xcd + 8 * (t >> 3);
    int e = g >> 3;
    int n0 = (g & 7) * 128;
    int m0 = (t & 7) * 128;
    int cnt = count[e];
    if (m0 >= cnt) return;
    int base_e = 0;
    for (int i = 0; i < e; i++) base_e += count[i];
    const unsigned short* Bp = wdb + (size_t)e * DD * II;

    __shared__ __align__(16) unsigned short As[8192];
    __shared__ __align__(16) unsigned short Bs[8192];

    int tid = threadIdx.x;
    int lane = tid & 63, wave = tid >> 6;
    int wm = wave & 1, wn = wave >> 1;
    int row16 = lane & 15, quad = lane >> 4;

    int qS = wave >> 1;
    int srow = (wave & 1) * 64 + (lane >> 2);
    int colS = ((lane & 3) ^ ((lane >> 3) & 3)) * 8;

    size_t arow[4];
#pragma unroll
    for (int c = 0; c < 4; c++) {
        int gr = m0 + srow + c * 16;
        int idx = (gr < cnt) ? gr : (cnt - 1);
        arow[c] = ((size_t)e * NTOK + idx) * II;
    }
    const unsigned short* gB0 = Bp + (size_t)(n0 + srow) * II + colS;

    f32x4 acc[4][4];
#pragma unroll
    for (int mi = 0; mi < 4; mi++)
#pragma unroll
        for (int ni = 0; ni < 4; ni++) acc[mi][ni] = (f32x4){0.f, 0.f, 0.f, 0.f};

    int qe = (quad ^ ((row16 >> 1) & 3)) * 8;

    for (int k0 = 0; k0 < II; k0 += 64) {
        int koff = k0 + qS * 32;
#pragma unroll
        for (int c = 0; c < 4; c++) {
            gl2lds16(hbuf + arow[c] + koff + colS, As + wave * 2048 + c * 512);
            gl2lds16(gB0 + (size_t)(c * 16) * II + koff, Bs + wave * 2048 + c * 512);
        }
        __syncthreads();

#pragma unroll
        for (int kk = 0; kk < 2; kk++) {
            bf16x8 a[4], b[4];
            int base = kk * 4096 + qe;
#pragma unroll
            for (int mi = 0; mi < 4; mi++)
                a[mi] = *(const bf16x8*)(As + base + (wm * 64 + mi * 16 + row16) * 32);
#pragma unroll
            for (int ni = 0; ni < 4; ni++)
                b[ni] = *(const bf16x8*)(Bs + base + (wn * 64 + ni * 16 + row16) * 32);
#pragma unroll
            for (int mi = 0; mi < 4; mi++)
#pragma unroll
                for (int ni = 0; ni < 4; ni++)
                    acc[mi][ni] = __builtin_amdgcn_mfma_f32_16x16x32_bf16(a[mi], b[ni], acc[mi][ni], 0, 0, 0);
        }
        __syncthreads();
    }

#pragma unroll
    for (int mi = 0; mi < 4; mi++) {
        int grb = m0 + wm * 64 + mi * 16 + quad * 4;
#pragma unroll
        for (int r = 0; r < 4; r++) {
            int gr = grb + r;
            if (gr >= cnt) continue;
            float* pr = pbuf + (size_t)(base_e + gr) * DD + n0 + wn * 64;
#pragma unroll
            for (int ni = 0; ni < 4; ni++)
                pr[ni * 16 + row16] = acc[mi][ni][r];
        }
    }
}

// tier-2 combine: y[t] = sum of t's 8 routed partials + shared partial.
__global__ __launch_bounds__(256) void combine_kernel(
    const float* __restrict__ pbuf, const int* __restrict__ count,
    const int* __restrict__ poslut, float* __restrict__ y)
{
    int t = blockIdx.x;
    int c4 = threadIdx.x;                  // float4 column index [0,256)
    float4 acc = make_float4(0.f, 0.f, 0.f, 0.f);
    int base = 0;
#pragma unroll
    for (int e = 0; e < NE; e++) {
        int p = poslut[e * NTOK + t];      // wave-uniform (same t per block)
        if (p >= 0) {
            float4 v = ((const float4*)(pbuf + (size_t)(base + p) * DD))[c4];
            acc.x += v.x; acc.y += v.y; acc.z += v.z; acc.w += v.w;
        }
        base += count[e];
    }
    // shared expert: pos == t
    {
        float4 v = ((const float4*)(pbuf + (size_t)(base + t) * DD))[c4];
        acc.x += v.x; acc.y += v.y; acc.z += v.z; acc.w += v.w;
    }
    ((float4*)(y + (size_t)t * DD))[c4] = acc;
}

// ======================= fallback path (round-0 kernels) ====================
__global__ __launch_bounds__(256) void gateup_fb(
    const unsigned short* __restrict__ xbf,
    const float* __restrict__ wg, const float* __restrict__ wu,
    const float* __restrict__ sgw, const float* __restrict__ suw,
    const int* __restrict__ count, const int* __restrict__ list,
    const float* __restrict__ scalebuf, unsigned short* __restrict__ hbuf)
{
    int e = blockIdx.z;
    int cnt = count[e];
    int m0 = blockIdx.x * BM;
    if (m0 >= cnt) return;
    int n0 = blockIdx.y * BN;
    const float* Bg = (e < NE) ? wg + (size_t)e * II * DD : sgw;
    const float* Bu = (e < NE) ? wu + (size_t)e * II * DD : suw;

    __shared__ __align__(16) unsigned short As[BM * LDA];
    __shared__ __align__(16) unsigned short Bgs[BN * LDA];
    __shared__ __align__(16) unsigned short Bus[BN * LDA];
    __shared__ int rowtok[BM];

    int tid = threadIdx.x;
    if (tid < BM) {
        int gr = m0 + tid;
        rowtok[tid] = (gr < cnt) ? list[e * NTOK + gr] : -1;
    }
    __syncthreads();

    int lane = tid & 63, wave = tid >> 6;
    int wm = wave >> 1, wn = wave & 1;
    int row16 = lane & 15, quad = lane >> 4;

    f32x4 accG[4][2], accU[4][2];
#pragma unroll
    for (int mi = 0; mi < 4; mi++)
#pragma unroll
        for (int ni = 0; ni < 2; ni++) {
            accG[mi][ni] = (f32x4){0.f, 0.f, 0.f, 0.f};
            accU[mi][ni] = (f32x4){0.f, 0.f, 0.f, 0.f};
        }

    for (int k0 = 0; k0 < DD; k0 += BK) {
#pragma unroll
        for (int i = 0; i < 2; i++) {
            int c = tid + 256 * i;
            int row = c >> 2, kc = (c & 3) * 8;
            int tok = rowtok[row];
            uint4 v = (tok >= 0) ? *(const uint4*)(xbf + (size_t)tok * DD + k0 + kc)
                                 : make_uint4(0u, 0u, 0u, 0u);
            *(uint4*)(As + row * LDA + kc) = v;
        }
#pragma unroll
        for (int i = 0; i < 2; i++) {
            int c = tid + 256 * i;
            int row = c >> 3, f = (c & 7) * 4;
            float4 vg = *(const float4*)(Bg + (size_t)(n0 + row) * DD + k0 + f);
            float4 vu = *(const float4*)(Bu + (size_t)(n0 + row) * DD + k0 + f);
            *(ushort4*)(Bgs + row * LDA + f) = make_ushort4(f2bf(vg.x), f2bf(vg.y), f2bf(vg.z), f2bf(vg.w));
            *(ushort4*)(Bus + row * LDA + f) = make_ushort4(f2bf(vu.x), f2bf(vu.y), f2bf(vu.z), f2bf(vu.w));
        }
        __syncthreads();

        bf16x8 af[4], bg[2], bu[2];
#pragma unroll
        for (int mi = 0; mi < 4; mi++)
            af[mi] = *(const bf16x8*)(As + (wm * 64 + mi * 16 + row16) * LDA + quad * 8);
#pragma unroll
        for (int ni = 0; ni < 2; ni++) {
            bg[ni] = *(const bf16x8*)(Bgs + (wn * 32 + ni * 16 + row16) * LDA + quad * 8);
            bu[ni] = *(const bf16x8*)(Bus + (wn * 32 + ni * 16 + row16) * LDA + quad * 8);
        }
#pragma unroll
        for (int mi = 0; mi < 4; mi++)
#pragma unroll
            for (int ni = 0; ni < 2; ni++) {
                accG[mi][ni] = __builtin_amdgcn_mfma_f32_16x16x32_bf16(af[mi], bg[ni], accG[mi][ni], 0, 0, 0);
                accU[mi][ni] = __builtin_amdgcn_mfma_f32_16x16x32_bf16(af[mi], bu[ni], accU[mi][ni], 0, 0, 0);
            }
        __syncthreads();
    }

#pragma unroll
    for (int mi = 0; mi < 4; mi++) {
        int mbase = wm * 64 + mi * 16 + quad * 4;
#pragma unroll
        for (int r = 0; r < 4; r++) {
            int gr = m0 + mbase + r;
            if (gr >= cnt) continue;
            float rs = scalebuf[e * NTOK + gr];
            size_t rowoff = ((size_t)e * NTOK + gr) * II + n0;
#pragma unroll
            for (int ni = 0; ni < 2; ni++) {
                int n = wn * 32 + ni * 16 + row16;
                float g = accG[mi][ni][r], u = accU[mi][ni][r];
                float h = g / (1.f + __expf(-g)) * u * rs;
                hbuf[rowoff + n] = f2bf(h);
            }
        }
    }
}

__global__ __launch_bounds__(256) void down_fb(
    const unsigned short* __restrict__ hbuf,
    const float* __restrict__ wd, const float* __restrict__ sdw,
    const int* __restrict__ count, const int* __restrict__ list,
    float* __restrict__ y)
{
    int e = blockIdx.z;
    int cnt = count[e];
    int m0 = blockIdx.x * BM;
    if (m0 >= cnt) return;
    int n0 = blockIdx.y * BN;
    const float* Bp = (e < NE) ? wd + (size_t)e * DD * II : sdw;

    __shared__ __align__(16) unsigned short As[BM * LDA];
    __shared__ __align__(16) unsigned short Bs[BN * LDA];

    int tid = threadIdx.x;
    int lane = tid & 63, wave = tid >> 6;
    int wm = wave >> 1, wn = wave & 1;
    int row16 = lane & 15, quad = lane >> 4;

    f32x4 acc[4][2];
#pragma unroll
    for (int mi = 0; mi < 4; mi++)
#pragma unroll
        for (int ni = 0; ni < 2; ni++) acc[mi][ni] = (f32x4){0.f, 0.f, 0.f, 0.f};

    const unsigned short* Abase = hbuf + ((size_t)e * NTOK + m0) * II;

    for (int k0 = 0; k0 < II; k0 += BK) {
#pragma unroll
        for (int i = 0; i < 2; i++) {
            int c = tid + 256 * i;
            int row = c >> 2, kc = (c & 3) * 8;
            uint4 v = (m0 + row < cnt) ? *(const uint4*)(Abase + (size_t)row * II + k0 + kc)
                                       : make_uint4(0u, 0u, 0u, 0u);
            *(uint4*)(As + row * LDA + kc) = v;
        }
#pragma unroll
        for (int i = 0; i < 2; i++) {
            int c = tid + 256 * i;
            int row = c >> 3, f = (c & 7) * 4;
            float4 v = *(const float4*)(Bp + (size_t)(n0 + row) * II + k0 + f);
            *(ushort4*)(Bs + row * LDA + f) = make_ushort4(f2bf(v.x), f2bf(v.y), f2bf(v.z), f2bf(v.w));
        }
        __syncthreads();

        bf16x8 af[4], bf[2];
#pragma unroll
        for (int mi = 0; mi < 4; mi++)
            af[mi] = *(const bf16x8*)(As + (wm * 64 + mi * 16 + row16) * LDA + quad * 8);
#pragma unroll
        for (int ni = 0; ni < 2; ni++)
            bf[ni] = *(const bf16x8*)(Bs + (wn * 32 + ni * 16 + row16) * LDA + quad * 8);
#pragma unroll
        for (int mi = 0; mi < 4; mi++)
#pragma unroll
            for (int ni = 0; ni < 2; ni++)
                acc[mi][ni] = __builtin_amdgcn_mfma_f32_16x16x32_bf16(af[mi], bf[ni], acc[mi][ni], 0, 0, 0);
        __syncthreads();
    }

#pragma unroll
    for (int mi = 0; mi < 4; mi++) {
        int mbase = wm * 64 + mi * 16 + quad * 4;
#pragma unroll
        for (int r = 0; r < 4; r++) {
            int gr = m0 + mbase + r;
            if (gr >= cnt) continue;
            int t = list[e * NTOK + gr];
#pragma unroll
            for (int ni = 0; ni < 2; ni++) {
                int n = wn * 32 + ni * 16 + row16;
                unsafeAtomicAdd(&y[(size_t)t * DD + n0 + n], acc[mi][ni][r]);
            }
        }
    }
}

extern "C" void kernel_launch(void* const* d_in, const int* in_sizes, int n_in,
                              void* d_out, int out_size, void* d_ws, size_t ws_size,
                              hipStream_t stream)
{
    const float* x    = (const float*)d_in[0];
    const float* gw   = (const float*)d_in[1];
    const float* bias = (const float*)d_in[2];
    const float* wg   = (const float*)d_in[3];
    const float* wu   = (const float*)d_in[4];
    const float* wd   = (const float*)d_in[5];
    const float* sgw  = (const float*)d_in[6];
    const float* suw  = (const float*)d_in[7];
    const float* sdw  = (const float*)d_in[8];
    float* y = (float*)d_out;

    char* ws = (char*)d_ws;
    unsigned short* xbf  = (unsigned short*)(ws + OFF_XBF);
    unsigned short* hbuf = (unsigned short*)(ws + OFF_H);
    unsigned short* wgb  = (unsigned short*)(ws + OFF_WG);
    unsigned short* wub  = (unsigned short*)(ws + OFF_WU);
    unsigned short* wdb  = (unsigned short*)(ws + OFF_WD);
    int*   list     = (int*)(ws + OFF_LIST);
    float* scalebuf = (float*)(ws + OFF_SCALE);
    int*   count    = (int*)(ws + OFF_CNT);
    int*   poslut   = (int*)(ws + OFF_POS);
    float* pbuf     = (float*)(ws + OFF_PBUF);

    bool big = (ws_size >= WS_NEED);
    bool pb  = (ws_size >= WS_NEED2);
    if (!big) {
        list     = (int*)(ws + 36ull * MB);
        scalebuf = (float*)(ws + 36ull * MB + 4ull * NEXP * NTOK);
        count    = (int*)(ws + 36ull * MB + 8ull * NEXP * NTOK);
    }

    // routing scratch aliased into hbuf region (consumed before gateup writes hbuf)
    unsigned int* emask = (unsigned int*)(ws + OFF_H);
    float*        tsc   = (float*)(ws + OFF_H + 4096);

    if (!(big && pb))
        hipMemsetAsync(d_out, 0, (size_t)NTOK * DD * sizeof(float), stream);

    prep_kernel<<<dim3(NTOK * DD / 4 / 256), 256, 0, stream>>>(x, xbf, list, scalebuf, count);
    route_score_kernel<<<dim3(NTOK / 4), 256, 0, stream>>>(x, gw, bias, emask, tsc);
    build_lists_kernel<<<dim3(NE), 1024, 0, stream>>>(emask, tsc, count, list, scalebuf,
                                                      pb ? poslut : (int*)nullptr);

    if (big) {
        wconv_kernel<<<dim3((unsigned)((size_t)NEXP * II * DD / 4 / 2048), 3), 256, 0, stream>>>(
            wg, wu, wd, sgw, suw, sdw, wgb, wub, wdb);
        gateup_kernel<<<dim3(NEXP * 8 * 8), 256, 0, stream>>>(
            xbf, wgb, wub, count, list, scalebuf, hbuf);
        if (pb) {
            down_pb_kernel<<<dim3(NEXP * 8 * 8), 256, 0, stream>>>(
                hbuf, wdb, count, pbuf);
            combine_kernel<<<dim3(NTOK), 256, 0, stream>>>(pbuf, count, poslut, y);
        } else {
            down_kernel<<<dim3(NEXP * 8 * 8), 256, 0, stream>>>(
                hbuf, wdb, count, list, y);
        }
    } else {
        gateup_fb<<<dim3(NTOK / BM, II / BN, NEXP), 256, 0, stream>>>(
            xbf, wg, wu, sgw, suw, count, list, scalebuf, hbuf);
        down_fb<<<dim3(NTOK / BM, DD / BN, NEXP), 256, 0, stream>>>(
            hbuf, wd, sdw, count, list, y);
    }
}

// Round 7
// 355.725 us; speedup vs baseline: 1.3928x; 1.1074x over previous
//
#include <hip/hip_runtime.h>
#include <hip/hip_bf16.h>

// ---------------------------------------------------------------------------
// AfmoE MoE: routing (sigmoid top-8) + 16 routed SwiGLU experts + shared
// expert as expert #16 via gather lists.
// Round 7: atomic-free two-phase routing (was 112us of serialized atomics).
// Round 8: 128x128 tile BK=64 GEMMs + LDS quad-swizzle -> gateup 79us.
// Round 9/10: REGRESSIONS (spill via forced min-waves; interleaved-B halves
//   A-reuse). Lesson: dual-acc @ (256,2) is gateup's optimum.
// Round 11: tier-2 down (partial rows + combine, no atomics) -> 394us.
// Round 12 (this round):
//   - wconv v3: profile showed 89us @ 2.4 TB/s, VALU 5% -> limited by 8B
//     stores + L3 pollution. Now: 2x adjacent float4 -> 1x ushort8 16B store,
//     fp32 reads nontemporal (keep bf16 pools L3-resident for the GEMMs).
//   - prep_kernel eliminated: route_score writes xbf as a side effect of the
//     x-rows it already reads; shared-expert list init moved to build_lists
//     block 16. One fewer launch + 4MB less traffic.
// ---------------------------------------------------------------------------

typedef __attribute__((ext_vector_type(8))) short bf16x8;
typedef __attribute__((ext_vector_type(4))) float f32x4;
typedef __attribute__((ext_vector_type(8))) unsigned short u16x8;

#define NTOK 1024   // B*S
#define DD   1024   // hidden
#define II   1024   // intermediate (same for shared)
#define NE   16     // routed experts
#define NEXP 17     // + shared expert as index 16
#define KSEL 8
#define RSCALE 2.826f

// fallback-path tiling
#define BM 128
#define BN 64
#define BK 32
#define LDA 40

// workspace layout (bytes)
#define MB (1024ull*1024ull)
#define OFF_XBF   0ull                         // ushort[NTOK*DD]          2 MiB
#define OFF_H     (2ull*MB)                    // ushort[NEXP*NTOK*II]    34 MiB
#define OFF_WG    (36ull*MB)                   // ushort[NEXP*II*DD]      34 MiB
#define OFF_WU    (70ull*MB)                   // ushort[NEXP*II*DD]      34 MiB
#define OFF_WD    (104ull*MB)                  // ushort[NEXP*DD*II]      34 MiB
#define OFF_LIST  (138ull*MB)                  // int[NEXP*NTOK]
#define OFF_SCALE (OFF_LIST + 4ull*NEXP*NTOK)  // float[NEXP*NTOK]
#define OFF_CNT   (OFF_SCALE + 4ull*NEXP*NTOK) // int[NEXP] (+ pad)
#define WS_NEED   (OFF_CNT + 4096ull)
// tier-2 (partial-sum down, no atomics):
#define OFF_POS   WS_NEED                      // int[NE*NTOK] = 64 KiB
#define OFF_PBUF  (OFF_POS + 4ull*NE*NTOK)     // float[9216*DD] = 36 MiB
#define WS_NEED2  (OFF_PBUF + 4ull*9216*DD)
// routing scratch aliased into the hbuf region (dead before gateup writes it):
//   emask: uint[NTOK] at OFF_H, tsc: float[NTOK*NE] at OFF_H+4096

__device__ __forceinline__ unsigned short f2bf(float f) {
    union { __hip_bfloat16 h; unsigned short u; } c;
    c.h = __float2bfloat16(f);
    return c.u;
}

__device__ __forceinline__ void gl2lds16(const unsigned short* g, unsigned short* l) {
    __builtin_amdgcn_global_load_lds(
        (const __attribute__((address_space(1))) void*)g,
        (__attribute__((address_space(3))) void*)l, 16, 0, 0);
}

__device__ __forceinline__ f32x4 ntload4(const float* p) {
    return __builtin_nontemporal_load((const f32x4*)p);
}

// --- convert all expert weights fp32 -> bf16 pools -------------------------
// v3: per thread 4x { two adjacent float4 (nontemporal) -> one ushort8 16B
// store }. nt loads keep the bf16 pools L3-resident for the GEMMs.
__global__ __launch_bounds__(256) void wconv_kernel(
    const float* __restrict__ wg, const float* __restrict__ wu, const float* __restrict__ wd,
    const float* __restrict__ sgw, const float* __restrict__ suw, const float* __restrict__ sdw,
    unsigned short* __restrict__ wgb, unsigned short* __restrict__ wub,
    unsigned short* __restrict__ wdb)
{
    const size_t ROUTED8 = (size_t)NE * II * DD / 8;   // 8-elem groups
    int p = blockIdx.y;
    const float* rsrc = (p == 0) ? wg : (p == 1) ? wu : wd;
    const float* ssrc = (p == 0) ? sgw : (p == 1) ? suw : sdw;
    unsigned short* dst = (p == 0) ? wgb : (p == 1) ? wub : wdb;

    size_t base8 = (size_t)blockIdx.x * 1024 + threadIdx.x;
    f32x4 a[4], b[4];
#pragma unroll
    for (int c = 0; c < 4; c++) {
        size_t g8 = base8 + c * 256;
        const float* src = (g8 < ROUTED8) ? rsrc + 8 * g8 : ssrc + 8 * (g8 - ROUTED8);
        a[c] = ntload4(src);
        b[c] = ntload4(src + 4);
    }
#pragma unroll
    for (int c = 0; c < 4; c++) {
        size_t g8 = base8 + c * 256;
        u16x8 o;
        o[0] = f2bf(a[c][0]); o[1] = f2bf(a[c][1]); o[2] = f2bf(a[c][2]); o[3] = f2bf(a[c][3]);
        o[4] = f2bf(b[c][0]); o[5] = f2bf(b[c][1]); o[6] = f2bf(b[c][2]); o[7] = f2bf(b[c][3]);
        *(u16x8*)(dst + 8 * g8) = o;
    }
}

// --- routing phase 1: scores + top-8 -> bitmask + scales; also emits xbf ---
__global__ __launch_bounds__(256) void route_score_kernel(
    const float* __restrict__ x, const float* __restrict__ gw,
    const float* __restrict__ bias, unsigned short* __restrict__ xbf,
    unsigned int* __restrict__ emask, float* __restrict__ tsc)
{
    int wave = threadIdx.x >> 6, lane = threadIdx.x & 63;
    int t = blockIdx.x * 4 + wave;

    const float4* xr = (const float4*)(x + (size_t)t * DD);
    ushort4* xw = (ushort4*)(xbf + (size_t)t * DD);
    float acc[NE];
#pragma unroll
    for (int e = 0; e < NE; e++) acc[e] = 0.f;
#pragma unroll
    for (int i = 0; i < DD / 64 / 4; i++) {
        float4 xv = xr[lane + 64 * i];
        xw[lane + 64 * i] = make_ushort4(f2bf(xv.x), f2bf(xv.y), f2bf(xv.z), f2bf(xv.w));
#pragma unroll
        for (int e = 0; e < NE; e++) {
            float4 w = ((const float4*)(gw + (size_t)e * DD))[lane + 64 * i];
            acc[e] += xv.x * w.x + xv.y * w.y + xv.z * w.z + xv.w * w.w;
        }
    }
#pragma unroll
    for (int e = 0; e < NE; e++) {
        float v = acc[e];
        for (int off = 32; off > 0; off >>= 1) v += __shfl_xor(v, off, 64);
        acc[e] = v;
    }
    if (lane == 0) {
        float sc[NE], sel[NE];
#pragma unroll
        for (int e = 0; e < NE; e++) {
            sc[e] = 1.f / (1.f + expf(-acc[e]));
            sel[e] = sc[e] + bias[e];
        }
        bool used[NE] = {};
        int inds[KSEL];
        float ssum = 0.f;
        for (int k = 0; k < KSEL; k++) {
            float best = -1e30f; int bi = 0;
            for (int e = 0; e < NE; e++)
                if (!used[e] && sel[e] > best) { best = sel[e]; bi = e; }
            used[bi] = true; inds[k] = bi; ssum += sc[bi];
        }
        float inv = RSCALE / ssum;
        unsigned int m = 0;
        for (int k = 0; k < KSEL; k++) {
            int e = inds[k];
            m |= (1u << e);
            tsc[(size_t)t * NE + e] = sc[e] * inv;
        }
        emask[t] = m;
    }
}

// --- routing phase 2: per-expert gather lists via ballot prefix-scan -------
// grid NEXP: block 16 initializes the shared-expert identity list.
// Writes poslut[e*NTOK+t] when tier-2 workspace available.
__global__ __launch_bounds__(1024) void build_lists_kernel(
    const unsigned int* __restrict__ emask, const float* __restrict__ tsc,
    int* __restrict__ count, int* __restrict__ list, float* __restrict__ scalebuf,
    int* __restrict__ poslut)
{
    int e = blockIdx.x;
    int t = threadIdx.x;
    if (e == NE) {
        list[NE * NTOK + t] = t;
        scalebuf[NE * NTOK + t] = 1.0f;
        if (t == 0) count[NE] = NTOK;
        return;
    }
    int lane = t & 63, wave = t >> 6;
    bool sel = (emask[t] >> e) & 1u;
    unsigned long long m = __ballot(sel);
    int posw = __popcll(m & ((1ull << lane) - 1ull));
    int wtot = __popcll(m);
    __shared__ int woff[16];
    if (lane == 0) woff[wave] = wtot;
    __syncthreads();
    if (t == 0) {
        int s = 0;
#pragma unroll
        for (int w = 0; w < 16; w++) { int v = woff[w]; woff[w] = s; s += v; }
        count[e] = s;
    }
    __syncthreads();
    int pos = woff[wave] + posw;
    if (sel) {
        list[e * NTOK + pos] = t;
        scalebuf[e * NTOK + pos] = tsc[(size_t)t * NE + e];
    }
    if (poslut) poslut[e * NTOK + t] = sel ? pos : -1;
}

// --- fused gate+up GEMM: BM=128 BN=128 BK=64, XCD-swizzled 1-D grid --------
// (round-8 structure, 78.9us measured). grid 1088 = 17 experts x 8 n-tiles
// x 8 m-tiles; all 8 m-tiles of one (e,n0) on one XCD for L2 weight reuse.
__global__ __launch_bounds__(256, 2) void gateup_kernel(
    const unsigned short* __restrict__ xbf,
    const unsigned short* __restrict__ wgb, const unsigned short* __restrict__ wub,
    const int* __restrict__ count, const int* __restrict__ list,
    const float* __restrict__ scalebuf, unsigned short* __restrict__ hbuf)
{
    int s = blockIdx.x;
    int xcd = s & 7, t = s >> 3;
    int g = xcd + 8 * (t >> 3);          // (e,n0) group, g%8 == xcd
    int e = g >> 3;
    int n0 = (g & 7) * 128;
    int m0 = (t & 7) * 128;
    int cnt = count[e];
    if (m0 >= cnt) return;
    const unsigned short* Bg = wgb + (size_t)e * II * DD;
    const unsigned short* Bu = wub + (size_t)e * II * DD;

    __shared__ __align__(16) unsigned short As[8192];
    __shared__ __align__(16) unsigned short Bgs[8192];
    __shared__ __align__(16) unsigned short Bus[8192];
    __shared__ int rowtok[128];

    int tid = threadIdx.x;
    if (tid < 128) {
        int gr = m0 + tid;
        rowtok[tid] = list[e * NTOK + ((gr < cnt) ? gr : (cnt - 1))];
    }
    __syncthreads();

    int lane = tid & 63, wave = tid >> 6;
    int wm = wave & 1, wn = wave >> 1;
    int row16 = lane & 15, quad = lane >> 4;

    int qS = wave >> 1;
    int srow = (wave & 1) * 64 + (lane >> 2);          // + c*16
    int colS = ((lane & 3) ^ ((lane >> 3) & 3)) * 8;   // pre-swizzled source chunk
    int tokr[4];
#pragma unroll
    for (int c = 0; c < 4; c++) tokr[c] = rowtok[srow + c * 16];
    const unsigned short* gBg0 = Bg + (size_t)(n0 + srow) * DD + colS;
    const unsigned short* gBu0 = Bu + (size_t)(n0 + srow) * DD + colS;

    f32x4 accG[4][4], accU[4][4];
#pragma unroll
    for (int mi = 0; mi < 4; mi++)
#pragma unroll
        for (int ni = 0; ni < 4; ni++) {
            accG[mi][ni] = (f32x4){0.f, 0.f, 0.f, 0.f};
            accU[mi][ni] = (f32x4){0.f, 0.f, 0.f, 0.f};
        }

    int qe = (quad ^ ((row16 >> 1) & 3)) * 8;          // swizzled read chunk

    for (int k0 = 0; k0 < DD; k0 += 64) {
        int koff = k0 + qS * 32;
#pragma unroll
        for (int c = 0; c < 4; c++) {
            gl2lds16(xbf + (size_t)tokr[c] * DD + koff + colS, As + wave * 2048 + c * 512);
            gl2lds16(gBg0 + (size_t)(c * 16) * DD + koff, Bgs + wave * 2048 + c * 512);
            gl2lds16(gBu0 + (size_t)(c * 16) * DD + koff, Bus + wave * 2048 + c * 512);
        }
        __syncthreads();

#pragma unroll
        for (int kk = 0; kk < 2; kk++) {
            bf16x8 a[4], bg[4], bu[4];
            int base = kk * 4096 + qe;
#pragma unroll
            for (int mi = 0; mi < 4; mi++)
                a[mi] = *(const bf16x8*)(As + base + (wm * 64 + mi * 16 + row16) * 32);
#pragma unroll
            for (int ni = 0; ni < 4; ni++) {
                bg[ni] = *(const bf16x8*)(Bgs + base + (wn * 64 + ni * 16 + row16) * 32);
                bu[ni] = *(const bf16x8*)(Bus + base + (wn * 64 + ni * 16 + row16) * 32);
            }
#pragma unroll
            for (int mi = 0; mi < 4; mi++)
#pragma unroll
                for (int ni = 0; ni < 4; ni++) {
                    accG[mi][ni] = __builtin_amdgcn_mfma_f32_16x16x32_bf16(a[mi], bg[ni], accG[mi][ni], 0, 0, 0);
                    accU[mi][ni] = __builtin_amdgcn_mfma_f32_16x16x32_bf16(a[mi], bu[ni], accU[mi][ni], 0, 0, 0);
                }
        }
        __syncthreads();
    }

#pragma unroll
    for (int mi = 0; mi < 4; mi++) {
        int grb = m0 + wm * 64 + mi * 16 + quad * 4;
#pragma unroll
        for (int r = 0; r < 4; r++) {
            int gr = grb + r;
            if (gr >= cnt) continue;
            float rs = scalebuf[e * NTOK + gr];
            size_t rowoff = ((size_t)e * NTOK + gr) * II + n0 + wn * 64;
#pragma unroll
            for (int ni = 0; ni < 4; ni++) {
                float g2 = accG[mi][ni][r], u = accU[mi][ni][r];
                float h = g2 / (1.f + __expf(-g2)) * u * rs;
                hbuf[rowoff + ni * 16 + row16] = f2bf(h);
            }
        }
    }
}

// --- down GEMM tier-1: atomic scatter into y -------------------------------
__global__ __launch_bounds__(256, 3) void down_kernel(
    const unsigned short* __restrict__ hbuf,
    const unsigned short* __restrict__ wdb,
    const int* __restrict__ count, const int* __restrict__ list,
    float* __restrict__ y)
{
    int s = blockIdx.x;
    int xcd = s & 7, t = s >> 3;
    int g = xcd + 8 * (t >> 3);
    int e = g >> 3;
    int n0 = (g & 7) * 128;
    int m0 = (t & 7) * 128;
    int cnt = count[e];
    if (m0 >= cnt) return;
    const unsigned short* Bp = wdb + (size_t)e * DD * II;

    __shared__ __align__(16) unsigned short As[8192];
    __shared__ __align__(16) unsigned short Bs[8192];

    int tid = threadIdx.x;
    int lane = tid & 63, wave = tid >> 6;
    int wm = wave & 1, wn = wave >> 1;
    int row16 = lane & 15, quad = lane >> 4;

    int qS = wave >> 1;
    int srow = (wave & 1) * 64 + (lane >> 2);
    int colS = ((lane & 3) ^ ((lane >> 3) & 3)) * 8;

    size_t arow[4];
#pragma unroll
    for (int c = 0; c < 4; c++) {
        int gr = m0 + srow + c * 16;
        int idx = (gr < cnt) ? gr : (cnt - 1);
        arow[c] = ((size_t)e * NTOK + idx) * II;
    }
    const unsigned short* gB0 = Bp + (size_t)(n0 + srow) * II + colS;

    f32x4 acc[4][4];
#pragma unroll
    for (int mi = 0; mi < 4; mi++)
#pragma unroll
        for (int ni = 0; ni < 4; ni++) acc[mi][ni] = (f32x4){0.f, 0.f, 0.f, 0.f};

    int qe = (quad ^ ((row16 >> 1) & 3)) * 8;

    for (int k0 = 0; k0 < II; k0 += 64) {
        int koff = k0 + qS * 32;
#pragma unroll
        for (int c = 0; c < 4; c++) {
            gl2lds16(hbuf + arow[c] + koff + colS, As + wave * 2048 + c * 512);
            gl2lds16(gB0 + (size_t)(c * 16) * II + koff, Bs + wave * 2048 + c * 512);
        }
        __syncthreads();

#pragma unroll
        for (int kk = 0; kk < 2; kk++) {
            bf16x8 a[4], b[4];
            int base = kk * 4096 + qe;
#pragma unroll
            for (int mi = 0; mi < 4; mi++)
                a[mi] = *(const bf16x8*)(As + base + (wm * 64 + mi * 16 + row16) * 32);
#pragma unroll
            for (int ni = 0; ni < 4; ni++)
                b[ni] = *(const bf16x8*)(Bs + base + (wn * 64 + ni * 16 + row16) * 32);
#pragma unroll
            for (int mi = 0; mi < 4; mi++)
#pragma unroll
                for (int ni = 0; ni < 4; ni++)
                    acc[mi][ni] = __builtin_amdgcn_mfma_f32_16x16x32_bf16(a[mi], b[ni], acc[mi][ni], 0, 0, 0);
        }
        __syncthreads();
    }

#pragma unroll
    for (int mi = 0; mi < 4; mi++) {
        int grb = m0 + wm * 64 + mi * 16 + quad * 4;
#pragma unroll
        for (int r = 0; r < 4; r++) {
            int gr = grb + r;
            if (gr >= cnt) continue;
            int tk = list[e * NTOK + gr];
            float* yr = y + (size_t)tk * DD + n0 + wn * 64;
#pragma unroll
            for (int ni = 0; ni < 4; ni++)
                unsafeAtomicAdd(yr + ni * 16 + row16, acc[mi][ni][r]);
        }
    }
}

// --- down GEMM tier-2: plain stores into compacted pbuf --------------------
__global__ __launch_bounds__(256, 3) void down_pb_kernel(
    const unsigned short* __restrict__ hbuf,
    const unsigned short* __restrict__ wdb,
    const int* __restrict__ count, float* __restrict__ pbuf)
{
    int s = blockIdx.x;
    int xcd = s & 7, t = s >> 3;
    int g = xcd + 8 * (t >> 3);
    int e = g >> 3;
    int n0 = (g & 7) * 128;
    int m0 = (t & 7) * 128;
    int cnt = count[e];
    if (m0 >= cnt) return;
    int base_e = 0;
    for (int i = 0; i < e; i++) base_e += count[i];
    const unsigned short* Bp = wdb + (size_t)e * DD * II;

    __shared__ __align__(16) unsigned short As[8192];
    __shared__ __align__(16) unsigned short Bs[8192];

    int tid = threadIdx.x;
    int lane = tid & 63, wave = tid >> 6;
    int wm = wave & 1, wn = wave >> 1;
    int row16 = lane & 15, quad = lane >> 4;

    int qS = wave >> 1;
    int srow = (wave & 1) * 64 + (lane >> 2);
    int colS = ((lane & 3) ^ ((lane >> 3) & 3)) * 8;

    size_t arow[4];
#pragma unroll
    for (int c = 0; c < 4; c++) {
        int gr = m0 + srow + c * 16;
        int idx = (gr < cnt) ? gr : (cnt - 1);
        arow[c] = ((size_t)e * NTOK + idx) * II;
    }
    const unsigned short* gB0 = Bp + (size_t)(n0 + srow) * II + colS;

    f32x4 acc[4][4];
#pragma unroll
    for (int mi = 0; mi < 4; mi++)
#pragma unroll
        for (int ni = 0; ni < 4; ni++) acc[mi][ni] = (f32x4){0.f, 0.f, 0.f, 0.f};

    int qe = (quad ^ ((row16 >> 1) & 3)) * 8;

    for (int k0 = 0; k0 < II; k0 += 64) {
        int koff = k0 + qS * 32;
#pragma unroll
        for (int c = 0; c < 4; c++) {
            gl2lds16(hbuf + arow[c] + koff + colS, As + wave * 2048 + c * 512);
            gl2lds16(gB0 + (size_t)(c * 16) * II + koff, Bs + wave * 2048 + c * 512);
        }
        __syncthreads();

#pragma unroll
        for (int kk = 0; kk < 2; kk++) {
            bf16x8 a[4], b[4];
            int base = kk * 4096 + qe;
#pragma unroll
            for (int mi = 0; mi < 4; mi++)
                a[mi] = *(const bf16x8*)(As + base + (wm * 64 + mi * 16 + row16) * 32);
#pragma unroll
            for (int ni = 0; ni < 4; ni++)
                b[ni] = *(const bf16x8*)(Bs + base + (wn * 64 + ni * 16 + row16) * 32);
#pragma unroll
            for (int mi = 0; mi < 4; mi++)
#pragma unroll
                for (int ni = 0; ni < 4; ni++)
                    acc[mi][ni] = __builtin_amdgcn_mfma_f32_16x16x32_bf16(a[mi], b[ni], acc[mi][ni], 0, 0, 0);
        }
        __syncthreads();
    }

#pragma unroll
    for (int mi = 0; mi < 4; mi++) {
        int grb = m0 + wm * 64 + mi * 16 + quad * 4;
#pragma unroll
        for (int r = 0; r < 4; r++) {
            int gr = grb + r;
            if (gr >= cnt) continue;
            float* pr = pbuf + (size_t)(base_e + gr) * DD + n0 + wn * 64;
#pragma unroll
            for (int ni = 0; ni < 4; ni++)
                pr[ni * 16 + row16] = acc[mi][ni][r];
        }
    }
}

// tier-2 combine: y[t] = sum of t's 8 routed partials + shared partial.
__global__ __launch_bounds__(256) void combine_kernel(
    const float* __restrict__ pbuf, const int* __restrict__ count,
    const int* __restrict__ poslut, float* __restrict__ y)
{
    int t = blockIdx.x;
    int c4 = threadIdx.x;
    float4 acc = make_float4(0.f, 0.f, 0.f, 0.f);
    int base = 0;
#pragma unroll
    for (int e = 0; e < NE; e++) {
        int p = poslut[e * NTOK + t];
        if (p >= 0) {
            float4 v = ((const float4*)(pbuf + (size_t)(base + p) * DD))[c4];
            acc.x += v.x; acc.y += v.y; acc.z += v.z; acc.w += v.w;
        }
        base += count[e];
    }
    {
        float4 v = ((const float4*)(pbuf + (size_t)(base + t) * DD))[c4];
        acc.x += v.x; acc.y += v.y; acc.z += v.z; acc.w += v.w;
    }
    ((float4*)(y + (size_t)t * DD))[c4] = acc;
}

// ======================= fallback path (round-0 kernels) ====================
__global__ __launch_bounds__(256) void gateup_fb(
    const unsigned short* __restrict__ xbf,
    const float* __restrict__ wg, const float* __restrict__ wu,
    const float* __restrict__ sgw, const float* __restrict__ suw,
    const int* __restrict__ count, const int* __restrict__ list,
    const float* __restrict__ scalebuf, unsigned short* __restrict__ hbuf)
{
    int e = blockIdx.z;
    int cnt = count[e];
    int m0 = blockIdx.x * BM;
    if (m0 >= cnt) return;
    int n0 = blockIdx.y * BN;
    const float* Bg = (e < NE) ? wg + (size_t)e * II * DD : sgw;
    const float* Bu = (e < NE) ? wu + (size_t)e * II * DD : suw;

    __shared__ __align__(16) unsigned short As[BM * LDA];
    __shared__ __align__(16) unsigned short Bgs[BN * LDA];
    __shared__ __align__(16) unsigned short Bus[BN * LDA];
    __shared__ int rowtok[BM];

    int tid = threadIdx.x;
    if (tid < BM) {
        int gr = m0 + tid;
        rowtok[tid] = (gr < cnt) ? list[e * NTOK + gr] : -1;
    }
    __syncthreads();

    int lane = tid & 63, wave = tid >> 6;
    int wm = wave >> 1, wn = wave & 1;
    int row16 = lane & 15, quad = lane >> 4;

    f32x4 accG[4][2], accU[4][2];
#pragma unroll
    for (int mi = 0; mi < 4; mi++)
#pragma unroll
        for (int ni = 0; ni < 2; ni++) {
            accG[mi][ni] = (f32x4){0.f, 0.f, 0.f, 0.f};
            accU[mi][ni] = (f32x4){0.f, 0.f, 0.f, 0.f};
        }

    for (int k0 = 0; k0 < DD; k0 += BK) {
#pragma unroll
        for (int i = 0; i < 2; i++) {
            int c = tid + 256 * i;
            int row = c >> 2, kc = (c & 3) * 8;
            int tok = rowtok[row];
            uint4 v = (tok >= 0) ? *(const uint4*)(xbf + (size_t)tok * DD + k0 + kc)
                                 : make_uint4(0u, 0u, 0u, 0u);
            *(uint4*)(As + row * LDA + kc) = v;
        }
#pragma unroll
        for (int i = 0; i < 2; i++) {
            int c = tid + 256 * i;
            int row = c >> 3, f = (c & 7) * 4;
            float4 vg = *(const float4*)(Bg + (size_t)(n0 + row) * DD + k0 + f);
            float4 vu = *(const float4*)(Bu + (size_t)(n0 + row) * DD + k0 + f);
            *(ushort4*)(Bgs + row * LDA + f) = make_ushort4(f2bf(vg.x), f2bf(vg.y), f2bf(vg.z), f2bf(vg.w));
            *(ushort4*)(Bus + row * LDA + f) = make_ushort4(f2bf(vu.x), f2bf(vu.y), f2bf(vu.z), f2bf(vu.w));
        }
        __syncthreads();

        bf16x8 af[4], bg[2], bu[2];
#pragma unroll
        for (int mi = 0; mi < 4; mi++)
            af[mi] = *(const bf16x8*)(As + (wm * 64 + mi * 16 + row16) * LDA + quad * 8);
#pragma unroll
        for (int ni = 0; ni < 2; ni++) {
            bg[ni] = *(const bf16x8*)(Bgs + (wn * 32 + ni * 16 + row16) * LDA + quad * 8);
            bu[ni] = *(const bf16x8*)(Bus + (wn * 32 + ni * 16 + row16) * LDA + quad * 8);
        }
#pragma unroll
        for (int mi = 0; mi < 4; mi++)
#pragma unroll
            for (int ni = 0; ni < 2; ni++) {
                accG[mi][ni] = __builtin_amdgcn_mfma_f32_16x16x32_bf16(af[mi], bg[ni], accG[mi][ni], 0, 0, 0);
                accU[mi][ni] = __builtin_amdgcn_mfma_f32_16x16x32_bf16(af[mi], bu[ni], accU[mi][ni], 0, 0, 0);
            }
        __syncthreads();
    }

#pragma unroll
    for (int mi = 0; mi < 4; mi++) {
        int mbase = wm * 64 + mi * 16 + quad * 4;
#pragma unroll
        for (int r = 0; r < 4; r++) {
            int gr = m0 + mbase + r;
            if (gr >= cnt) continue;
            float rs = scalebuf[e * NTOK + gr];
            size_t rowoff = ((size_t)e * NTOK + gr) * II + n0;
#pragma unroll
            for (int ni = 0; ni < 2; ni++) {
                int n = wn * 32 + ni * 16 + row16;
                float g = accG[mi][ni][r], u = accU[mi][ni][r];
                float h = g / (1.f + __expf(-g)) * u * rs;
                hbuf[rowoff + n] = f2bf(h);
            }
        }
    }
}

__global__ __launch_bounds__(256) void down_fb(
    const unsigned short* __restrict__ hbuf,
    const float* __restrict__ wd, const float* __restrict__ sdw,
    const int* __restrict__ count, const int* __restrict__ list,
    float* __restrict__ y)
{
    int e = blockIdx.z;
    int cnt = count[e];
    int m0 = blockIdx.x * BM;
    if (m0 >= cnt) return;
    int n0 = blockIdx.y * BN;
    const float* Bp = (e < NE) ? wd + (size_t)e * DD * II : sdw;

    __shared__ __align__(16) unsigned short As[BM * LDA];
    __shared__ __align__(16) unsigned short Bs[BN * LDA];

    int tid = threadIdx.x;
    int lane = tid & 63, wave = tid >> 6;
    int wm = wave >> 1, wn = wave & 1;
    int row16 = lane & 15, quad = lane >> 4;

    f32x4 acc[4][2];
#pragma unroll
    for (int mi = 0; mi < 4; mi++)
#pragma unroll
        for (int ni = 0; ni < 2; ni++) acc[mi][ni] = (f32x4){0.f, 0.f, 0.f, 0.f};

    const unsigned short* Abase = hbuf + ((size_t)e * NTOK + m0) * II;

    for (int k0 = 0; k0 < II; k0 += BK) {
#pragma unroll
        for (int i = 0; i < 2; i++) {
            int c = tid + 256 * i;
            int row = c >> 2, kc = (c & 3) * 8;
            uint4 v = (m0 + row < cnt) ? *(const uint4*)(Abase + (size_t)row * II + k0 + kc)
                                       : make_uint4(0u, 0u, 0u, 0u);
            *(uint4*)(As + row * LDA + kc) = v;
        }
#pragma unroll
        for (int i = 0; i < 2; i++) {
            int c = tid + 256 * i;
            int row = c >> 3, f = (c & 7) * 4;
            float4 v = *(const float4*)(Bp + (size_t)(n0 + row) * II + k0 + f);
            *(ushort4*)(Bs + row * LDA + f) = make_ushort4(f2bf(v.x), f2bf(v.y), f2bf(v.z), f2bf(v.w));
        }
        __syncthreads();

        bf16x8 af[4], bf[2];
#pragma unroll
        for (int mi = 0; mi < 4; mi++)
            af[mi] = *(const bf16x8*)(As + (wm * 64 + mi * 16 + row16) * LDA + quad * 8);
#pragma unroll
        for (int ni = 0; ni < 2; ni++)
            bf[ni] = *(const bf16x8*)(Bs + (wn * 32 + ni * 16 + row16) * LDA + quad * 8);
#pragma unroll
        for (int mi = 0; mi < 4; mi++)
#pragma unroll
            for (int ni = 0; ni < 2; ni++)
                acc[mi][ni] = __builtin_amdgcn_mfma_f32_16x16x32_bf16(af[mi], bf[ni], acc[mi][ni], 0, 0, 0);
        __syncthreads();
    }

#pragma unroll
    for (int mi = 0; mi < 4; mi++) {
        int mbase = wm * 64 + mi * 16 + quad * 4;
#pragma unroll
        for (int r = 0; r < 4; r++) {
            int gr = m0 + mbase + r;
            if (gr >= cnt) continue;
            int t = list[e * NTOK + gr];
#pragma unroll
            for (int ni = 0; ni < 2; ni++) {
                int n = wn * 32 + ni * 16 + row16;
                unsafeAtomicAdd(&y[(size_t)t * DD + n0 + n], acc[mi][ni][r]);
            }
        }
    }
}

extern "C" void kernel_launch(void* const* d_in, const int* in_sizes, int n_in,
                              void* d_out, int out_size, void* d_ws, size_t ws_size,
                              hipStream_t stream)
{
    const float* x    = (const float*)d_in[0];
    const float* gw   = (const float*)d_in[1];
    const float* bias = (const float*)d_in[2];
    const float* wg   = (const float*)d_in[3];
    const float* wu   = (const float*)d_in[4];
    const float* wd   = (const float*)d_in[5];
    const float* sgw  = (const float*)d_in[6];
    const float* suw  = (const float*)d_in[7];
    const float* sdw  = (const float*)d_in[8];
    float* y = (float*)d_out;

    char* ws = (char*)d_ws;
    unsigned short* xbf  = (unsigned short*)(ws + OFF_XBF);
    unsigned short* hbuf = (unsigned short*)(ws + OFF_H);
    unsigned short* wgb  = (unsigned short*)(ws + OFF_WG);
    unsigned short* wub  = (unsigned short*)(ws + OFF_WU);
    unsigned short* wdb  = (unsigned short*)(ws + OFF_WD);
    int*   list     = (int*)(ws + OFF_LIST);
    float* scalebuf = (float*)(ws + OFF_SCALE);
    int*   count    = (int*)(ws + OFF_CNT);
    int*   poslut   = (int*)(ws + OFF_POS);
    float* pbuf     = (float*)(ws + OFF_PBUF);

    bool big = (ws_size >= WS_NEED);
    bool pb  = (ws_size >= WS_NEED2);
    if (!big) {
        list     = (int*)(ws + 36ull * MB);
        scalebuf = (float*)(ws + 36ull * MB + 4ull * NEXP * NTOK);
        count    = (int*)(ws + 36ull * MB + 8ull * NEXP * NTOK);
    }

    // routing scratch aliased into hbuf region (consumed before gateup writes hbuf)
    unsigned int* emask = (unsigned int*)(ws + OFF_H);
    float*        tsc   = (float*)(ws + OFF_H + 4096);

    if (!(big && pb))
        hipMemsetAsync(d_out, 0, (size_t)NTOK * DD * sizeof(float), stream);

    route_score_kernel<<<dim3(NTOK / 4), 256, 0, stream>>>(x, gw, bias, xbf, emask, tsc);
    build_lists_kernel<<<dim3(NEXP), 1024, 0, stream>>>(emask, tsc, count, list, scalebuf,
                                                        pb ? poslut : (int*)nullptr);

    if (big) {
        wconv_kernel<<<dim3((unsigned)((size_t)NEXP * II * DD / 8 / 1024), 3), 256, 0, stream>>>(
            wg, wu, wd, sgw, suw, sdw, wgb, wub, wdb);
        gateup_kernel<<<dim3(NEXP * 8 * 8), 256, 0, stream>>>(
            xbf, wgb, wub, count, list, scalebuf, hbuf);
        if (pb) {
            down_pb_kernel<<<dim3(NEXP * 8 * 8), 256, 0, stream>>>(
                hbuf, wdb, count, pbuf);
            combine_kernel<<<dim3(NTOK), 256, 0, stream>>>(pbuf, count, poslut, y);
        } else {
            down_kernel<<<dim3(NEXP * 8 * 8), 256, 0, stream>>>(
                hbuf, wdb, count, list, y);
        }
    } else {
        gateup_fb<<<dim3(NTOK / BM, II / BN, NEXP), 256, 0, stream>>>(
            xbf, wg, wu, sgw, suw, count, list, scalebuf, hbuf);
        down_fb<<<dim3(NTOK / BM, DD / BN, NEXP), 256, 0, stream>>>(
            hbuf, wd, sdw, count, list, y);
    }
}

// Round 8
// 335.668 us; speedup vs baseline: 1.4760x; 1.0598x over previous
//
#include <hip/hip_runtime.h>
#include <hip/hip_bf16.h>

// ---------------------------------------------------------------------------
// AfmoE MoE: routing (sigmoid top-8) + 16 routed SwiGLU experts + shared
// expert as expert #16 via gather lists.
// Round 7: atomic-free two-phase routing (was 112us of serialized atomics).
// Round 8: 128x128 tile BK=64 GEMMs + LDS quad-swizzle -> gateup 79us.
// Round 9/10: REGRESSIONS (spill via forced min-waves; interleaved-B halves
//   A-reuse). Lesson: dual-acc @ (256,2) is gateup's optimum (2 waves/SIMD,
//   232/256 regs -- structural).
// Round 11: tier-2 down (partial rows + combine, no atomics).
// Round 12: wconv v3 (16B stores + nontemporal fp32 reads) + prep fused into
//   route_score -> 355.7us. Side effect: gateup 79->63.6 (bf16 pools stay
//   L3-resident).
// Round 13 (this round): route_score + wconv fused into ONE prologue_kernel
//   via block-range partition (blocks 0..255 route, 256+ convert). The two
//   are independent; routing is latency-bound (BW idle) and wconv is
//   BW-bound -> true overlap + one fewer launch. ~150us of the total tracks
//   kernel count (launch/drain overhead), so cutting launches is a lever.
// ---------------------------------------------------------------------------

typedef __attribute__((ext_vector_type(8))) short bf16x8;
typedef __attribute__((ext_vector_type(4))) float f32x4;
typedef __attribute__((ext_vector_type(8))) unsigned short u16x8;

#define NTOK 1024   // B*S
#define DD   1024   // hidden
#define II   1024   // intermediate (same for shared)
#define NE   16     // routed experts
#define NEXP 17     // + shared expert as index 16
#define KSEL 8
#define RSCALE 2.826f

// wconv geometry (8-elem groups)
#define WCONV_BLOCKS 2176          // (NEXP*II*DD/8)/1024 per matrix
#define ROUTE_BLOCKS 256

// fallback-path tiling
#define BM 128
#define BN 64
#define BK 32
#define LDA 40

// workspace layout (bytes)
#define MB (1024ull*1024ull)
#define OFF_XBF   0ull                         // ushort[NTOK*DD]          2 MiB
#define OFF_H     (2ull*MB)                    // ushort[NEXP*NTOK*II]    34 MiB
#define OFF_WG    (36ull*MB)                   // ushort[NEXP*II*DD]      34 MiB
#define OFF_WU    (70ull*MB)                   // ushort[NEXP*II*DD]      34 MiB
#define OFF_WD    (104ull*MB)                  // ushort[NEXP*DD*II]      34 MiB
#define OFF_LIST  (138ull*MB)                  // int[NEXP*NTOK]
#define OFF_SCALE (OFF_LIST + 4ull*NEXP*NTOK)  // float[NEXP*NTOK]
#define OFF_CNT   (OFF_SCALE + 4ull*NEXP*NTOK) // int[NEXP] (+ pad)
#define WS_NEED   (OFF_CNT + 4096ull)
// tier-2 (partial-sum down, no atomics):
#define OFF_POS   WS_NEED                      // int[NE*NTOK] = 64 KiB
#define OFF_PBUF  (OFF_POS + 4ull*NE*NTOK)     // float[9216*DD] = 36 MiB
#define WS_NEED2  (OFF_PBUF + 4ull*9216*DD)
// routing scratch aliased into the hbuf region (dead before gateup writes it):
//   emask: uint[NTOK] at OFF_H, tsc: float[NTOK*NE] at OFF_H+4096

__device__ __forceinline__ unsigned short f2bf(float f) {
    union { __hip_bfloat16 h; unsigned short u; } c;
    c.h = __float2bfloat16(f);
    return c.u;
}

__device__ __forceinline__ void gl2lds16(const unsigned short* g, unsigned short* l) {
    __builtin_amdgcn_global_load_lds(
        (const __attribute__((address_space(1))) void*)g,
        (__attribute__((address_space(3))) void*)l, 16, 0, 0);
}

__device__ __forceinline__ f32x4 ntload4(const float* p) {
    return __builtin_nontemporal_load((const f32x4*)p);
}

// --- fused prologue: routing (blocks 0..255) + weight conversion (256+) ----
// Routing: one wave per token -> scores, top-8, bitmask+scales, xbf emit.
// Wconv: per thread 4x { two adjacent float4 (nontemporal) -> ushort8 }.
__global__ __launch_bounds__(256) void prologue_kernel(
    const float* __restrict__ x, const float* __restrict__ gw,
    const float* __restrict__ bias, unsigned short* __restrict__ xbf,
    unsigned int* __restrict__ emask, float* __restrict__ tsc,
    const float* __restrict__ wg, const float* __restrict__ wu, const float* __restrict__ wd,
    const float* __restrict__ sgw, const float* __restrict__ suw, const float* __restrict__ sdw,
    unsigned short* __restrict__ wgb, unsigned short* __restrict__ wub,
    unsigned short* __restrict__ wdb)
{
    if (blockIdx.x >= ROUTE_BLOCKS) {
        // ---------------- weight conversion ----------------
        int wb = blockIdx.x - ROUTE_BLOCKS;
        int p  = wb / WCONV_BLOCKS;
        int bx = wb - p * WCONV_BLOCKS;
        const size_t ROUTED8 = (size_t)NE * II * DD / 8;
        const float* rsrc = (p == 0) ? wg : (p == 1) ? wu : wd;
        const float* ssrc = (p == 0) ? sgw : (p == 1) ? suw : sdw;
        unsigned short* dst = (p == 0) ? wgb : (p == 1) ? wub : wdb;

        size_t base8 = (size_t)bx * 1024 + threadIdx.x;
        f32x4 a[4], b[4];
#pragma unroll
        for (int c = 0; c < 4; c++) {
            size_t g8 = base8 + c * 256;
            const float* src = (g8 < ROUTED8) ? rsrc + 8 * g8 : ssrc + 8 * (g8 - ROUTED8);
            a[c] = ntload4(src);
            b[c] = ntload4(src + 4);
        }
#pragma unroll
        for (int c = 0; c < 4; c++) {
            size_t g8 = base8 + c * 256;
            u16x8 o;
            o[0] = f2bf(a[c][0]); o[1] = f2bf(a[c][1]); o[2] = f2bf(a[c][2]); o[3] = f2bf(a[c][3]);
            o[4] = f2bf(b[c][0]); o[5] = f2bf(b[c][1]); o[6] = f2bf(b[c][2]); o[7] = f2bf(b[c][3]);
            *(u16x8*)(dst + 8 * g8) = o;
        }
        return;
    }

    // ---------------- routing ----------------
    int wave = threadIdx.x >> 6, lane = threadIdx.x & 63;
    int t = blockIdx.x * 4 + wave;

    const float4* xr = (const float4*)(x + (size_t)t * DD);
    ushort4* xw = (ushort4*)(xbf + (size_t)t * DD);
    float acc[NE];
#pragma unroll
    for (int e = 0; e < NE; e++) acc[e] = 0.f;
#pragma unroll
    for (int i = 0; i < DD / 64 / 4; i++) {
        float4 xv = xr[lane + 64 * i];
        xw[lane + 64 * i] = make_ushort4(f2bf(xv.x), f2bf(xv.y), f2bf(xv.z), f2bf(xv.w));
#pragma unroll
        for (int e = 0; e < NE; e++) {
            float4 w = ((const float4*)(gw + (size_t)e * DD))[lane + 64 * i];
            acc[e] += xv.x * w.x + xv.y * w.y + xv.z * w.z + xv.w * w.w;
        }
    }
#pragma unroll
    for (int e = 0; e < NE; e++) {
        float v = acc[e];
        for (int off = 32; off > 0; off >>= 1) v += __shfl_xor(v, off, 64);
        acc[e] = v;
    }
    if (lane == 0) {
        float sc[NE], sel[NE];
#pragma unroll
        for (int e = 0; e < NE; e++) {
            sc[e] = 1.f / (1.f + expf(-acc[e]));
            sel[e] = sc[e] + bias[e];
        }
        bool used[NE] = {};
        int inds[KSEL];
        float ssum = 0.f;
        for (int k = 0; k < KSEL; k++) {
            float best = -1e30f; int bi = 0;
            for (int e = 0; e < NE; e++)
                if (!used[e] && sel[e] > best) { best = sel[e]; bi = e; }
            used[bi] = true; inds[k] = bi; ssum += sc[bi];
        }
        float inv = RSCALE / ssum;
        unsigned int m = 0;
        for (int k = 0; k < KSEL; k++) {
            int e = inds[k];
            m |= (1u << e);
            tsc[(size_t)t * NE + e] = sc[e] * inv;
        }
        emask[t] = m;
    }
}

// --- routing phase 2: per-expert gather lists via ballot prefix-scan -------
// grid NEXP: block 16 initializes the shared-expert identity list.
__global__ __launch_bounds__(1024) void build_lists_kernel(
    const unsigned int* __restrict__ emask, const float* __restrict__ tsc,
    int* __restrict__ count, int* __restrict__ list, float* __restrict__ scalebuf,
    int* __restrict__ poslut)
{
    int e = blockIdx.x;
    int t = threadIdx.x;
    if (e == NE) {
        list[NE * NTOK + t] = t;
        scalebuf[NE * NTOK + t] = 1.0f;
        if (t == 0) count[NE] = NTOK;
        return;
    }
    int lane = t & 63, wave = t >> 6;
    bool sel = (emask[t] >> e) & 1u;
    unsigned long long m = __ballot(sel);
    int posw = __popcll(m & ((1ull << lane) - 1ull));
    int wtot = __popcll(m);
    __shared__ int woff[16];
    if (lane == 0) woff[wave] = wtot;
    __syncthreads();
    if (t == 0) {
        int s = 0;
#pragma unroll
        for (int w = 0; w < 16; w++) { int v = woff[w]; woff[w] = s; s += v; }
        count[e] = s;
    }
    __syncthreads();
    int pos = woff[wave] + posw;
    if (sel) {
        list[e * NTOK + pos] = t;
        scalebuf[e * NTOK + pos] = tsc[(size_t)t * NE + e];
    }
    if (poslut) poslut[e * NTOK + t] = sel ? pos : -1;
}

// --- fused gate+up GEMM: BM=128 BN=128 BK=64, XCD-swizzled 1-D grid --------
__global__ __launch_bounds__(256, 2) void gateup_kernel(
    const unsigned short* __restrict__ xbf,
    const unsigned short* __restrict__ wgb, const unsigned short* __restrict__ wub,
    const int* __restrict__ count, const int* __restrict__ list,
    const float* __restrict__ scalebuf, unsigned short* __restrict__ hbuf)
{
    int s = blockIdx.x;
    int xcd = s & 7, t = s >> 3;
    int g = xcd + 8 * (t >> 3);          // (e,n0) group, g%8 == xcd
    int e = g >> 3;
    int n0 = (g & 7) * 128;
    int m0 = (t & 7) * 128;
    int cnt = count[e];
    if (m0 >= cnt) return;
    const unsigned short* Bg = wgb + (size_t)e * II * DD;
    const unsigned short* Bu = wub + (size_t)e * II * DD;

    __shared__ __align__(16) unsigned short As[8192];
    __shared__ __align__(16) unsigned short Bgs[8192];
    __shared__ __align__(16) unsigned short Bus[8192];
    __shared__ int rowtok[128];

    int tid = threadIdx.x;
    if (tid < 128) {
        int gr = m0 + tid;
        rowtok[tid] = list[e * NTOK + ((gr < cnt) ? gr : (cnt - 1))];
    }
    __syncthreads();

    int lane = tid & 63, wave = tid >> 6;
    int wm = wave & 1, wn = wave >> 1;
    int row16 = lane & 15, quad = lane >> 4;

    int qS = wave >> 1;
    int srow = (wave & 1) * 64 + (lane >> 2);          // + c*16
    int colS = ((lane & 3) ^ ((lane >> 3) & 3)) * 8;   // pre-swizzled source chunk
    int tokr[4];
#pragma unroll
    for (int c = 0; c < 4; c++) tokr[c] = rowtok[srow + c * 16];
    const unsigned short* gBg0 = Bg + (size_t)(n0 + srow) * DD + colS;
    const unsigned short* gBu0 = Bu + (size_t)(n0 + srow) * DD + colS;

    f32x4 accG[4][4], accU[4][4];
#pragma unroll
    for (int mi = 0; mi < 4; mi++)
#pragma unroll
        for (int ni = 0; ni < 4; ni++) {
            accG[mi][ni] = (f32x4){0.f, 0.f, 0.f, 0.f};
            accU[mi][ni] = (f32x4){0.f, 0.f, 0.f, 0.f};
        }

    int qe = (quad ^ ((row16 >> 1) & 3)) * 8;          // swizzled read chunk

    for (int k0 = 0; k0 < DD; k0 += 64) {
        int koff = k0 + qS * 32;
#pragma unroll
        for (int c = 0; c < 4; c++) {
            gl2lds16(xbf + (size_t)tokr[c] * DD + koff + colS, As + wave * 2048 + c * 512);
            gl2lds16(gBg0 + (size_t)(c * 16) * DD + koff, Bgs + wave * 2048 + c * 512);
            gl2lds16(gBu0 + (size_t)(c * 16) * DD + koff, Bus + wave * 2048 + c * 512);
        }
        __syncthreads();

#pragma unroll
        for (int kk = 0; kk < 2; kk++) {
            bf16x8 a[4], bg[4], bu[4];
            int base = kk * 4096 + qe;
#pragma unroll
            for (int mi = 0; mi < 4; mi++)
                a[mi] = *(const bf16x8*)(As + base + (wm * 64 + mi * 16 + row16) * 32);
#pragma unroll
            for (int ni = 0; ni < 4; ni++) {
                bg[ni] = *(const bf16x8*)(Bgs + base + (wn * 64 + ni * 16 + row16) * 32);
                bu[ni] = *(const bf16x8*)(Bus + base + (wn * 64 + ni * 16 + row16) * 32);
            }
#pragma unroll
            for (int mi = 0; mi < 4; mi++)
#pragma unroll
                for (int ni = 0; ni < 4; ni++) {
                    accG[mi][ni] = __builtin_amdgcn_mfma_f32_16x16x32_bf16(a[mi], bg[ni], accG[mi][ni], 0, 0, 0);
                    accU[mi][ni] = __builtin_amdgcn_mfma_f32_16x16x32_bf16(a[mi], bu[ni], accU[mi][ni], 0, 0, 0);
                }
        }
        __syncthreads();
    }

#pragma unroll
    for (int mi = 0; mi < 4; mi++) {
        int grb = m0 + wm * 64 + mi * 16 + quad * 4;
#pragma unroll
        for (int r = 0; r < 4; r++) {
            int gr = grb + r;
            if (gr >= cnt) continue;
            float rs = scalebuf[e * NTOK + gr];
            size_t rowoff = ((size_t)e * NTOK + gr) * II + n0 + wn * 64;
#pragma unroll
            for (int ni = 0; ni < 4; ni++) {
                float g2 = accG[mi][ni][r], u = accU[mi][ni][r];
                float h = g2 / (1.f + __expf(-g2)) * u * rs;
                hbuf[rowoff + ni * 16 + row16] = f2bf(h);
            }
        }
    }
}

// --- down GEMM tier-1: atomic scatter into y -------------------------------
__global__ __launch_bounds__(256, 3) void down_kernel(
    const unsigned short* __restrict__ hbuf,
    const unsigned short* __restrict__ wdb,
    const int* __restrict__ count, const int* __restrict__ list,
    float* __restrict__ y)
{
    int s = blockIdx.x;
    int xcd = s & 7, t = s >> 3;
    int g = xcd + 8 * (t >> 3);
    int e = g >> 3;
    int n0 = (g & 7) * 128;
    int m0 = (t & 7) * 128;
    int cnt = count[e];
    if (m0 >= cnt) return;
    const unsigned short* Bp = wdb + (size_t)e * DD * II;

    __shared__ __align__(16) unsigned short As[8192];
    __shared__ __align__(16) unsigned short Bs[8192];

    int tid = threadIdx.x;
    int lane = tid & 63, wave = tid >> 6;
    int wm = wave & 1, wn = wave >> 1;
    int row16 = lane & 15, quad = lane >> 4;

    int qS = wave >> 1;
    int srow = (wave & 1) * 64 + (lane >> 2);
    int colS = ((lane & 3) ^ ((lane >> 3) & 3)) * 8;

    size_t arow[4];
#pragma unroll
    for (int c = 0; c < 4; c++) {
        int gr = m0 + srow + c * 16;
        int idx = (gr < cnt) ? gr : (cnt - 1);
        arow[c] = ((size_t)e * NTOK + idx) * II;
    }
    const unsigned short* gB0 = Bp + (size_t)(n0 + srow) * II + colS;

    f32x4 acc[4][4];
#pragma unroll
    for (int mi = 0; mi < 4; mi++)
#pragma unroll
        for (int ni = 0; ni < 4; ni++) acc[mi][ni] = (f32x4){0.f, 0.f, 0.f, 0.f};

    int qe = (quad ^ ((row16 >> 1) & 3)) * 8;

    for (int k0 = 0; k0 < II; k0 += 64) {
        int koff = k0 + qS * 32;
#pragma unroll
        for (int c = 0; c < 4; c++) {
            gl2lds16(hbuf + arow[c] + koff + colS, As + wave * 2048 + c * 512);
            gl2lds16(gB0 + (size_t)(c * 16) * II + koff, Bs + wave * 2048 + c * 512);
        }
        __syncthreads();

#pragma unroll
        for (int kk = 0; kk < 2; kk++) {
            bf16x8 a[4], b[4];
            int base = kk * 4096 + qe;
#pragma unroll
            for (int mi = 0; mi < 4; mi++)
                a[mi] = *(const bf16x8*)(As + base + (wm * 64 + mi * 16 + row16) * 32);
#pragma unroll
            for (int ni = 0; ni < 4; ni++)
                b[ni] = *(const bf16x8*)(Bs + base + (wn * 64 + ni * 16 + row16) * 32);
#pragma unroll
            for (int mi = 0; mi < 4; mi++)
#pragma unroll
                for (int ni = 0; ni < 4; ni++)
                    acc[mi][ni] = __builtin_amdgcn_mfma_f32_16x16x32_bf16(a[mi], b[ni], acc[mi][ni], 0, 0, 0);
        }
        __syncthreads();
    }

#pragma unroll
    for (int mi = 0; mi < 4; mi++) {
        int grb = m0 + wm * 64 + mi * 16 + quad * 4;
#pragma unroll
        for (int r = 0; r < 4; r++) {
            int gr = grb + r;
            if (gr >= cnt) continue;
            int tk = list[e * NTOK + gr];
            float* yr = y + (size_t)tk * DD + n0 + wn * 64;
#pragma unroll
            for (int ni = 0; ni < 4; ni++)
                unsafeAtomicAdd(yr + ni * 16 + row16, acc[mi][ni][r]);
        }
    }
}

// --- down GEMM tier-2: plain stores into compacted pbuf --------------------
__global__ __launch_bounds__(256, 3) void down_pb_kernel(
    const unsigned short* __restrict__ hbuf,
    const unsigned short* __restrict__ wdb,
    const int* __restrict__ count, float* __restrict__ pbuf)
{
    int s = blockIdx.x;
    int xcd = s & 7, t = s >> 3;
    int g = xcd + 8 * (t >> 3);
    int e = g >> 3;
    int n0 = (g & 7) * 128;
    int m0 = (t & 7) * 128;
    int cnt = count[e];
    if (m0 >= cnt) return;
    int base_e = 0;
    for (int i = 0; i < e; i++) base_e += count[i];
    const unsigned short* Bp = wdb + (size_t)e * DD * II;

    __shared__ __align__(16) unsigned short As[8192];
    __shared__ __align__(16) unsigned short Bs[8192];

    int tid = threadIdx.x;
    int lane = tid & 63, wave = tid >> 6;
    int wm = wave & 1, wn = wave >> 1;
    int row16 = lane & 15, quad = lane >> 4;

    int qS = wave >> 1;
    int srow = (wave & 1) * 64 + (lane >> 2);
    int colS = ((lane & 3) ^ ((lane >> 3) & 3)) * 8;

    size_t arow[4];
#pragma unroll
    for (int c = 0; c < 4; c++) {
        int gr = m0 + srow + c * 16;
        int idx = (gr < cnt) ? gr : (cnt - 1);
        arow[c] = ((size_t)e * NTOK + idx) * II;
    }
    const unsigned short* gB0 = Bp + (size_t)(n0 + srow) * II + colS;

    f32x4 acc[4][4];
#pragma unroll
    for (int mi = 0; mi < 4; mi++)
#pragma unroll
        for (int ni = 0; ni < 4; ni++) acc[mi][ni] = (f32x4){0.f, 0.f, 0.f, 0.f};

    int qe = (quad ^ ((row16 >> 1) & 3)) * 8;

    for (int k0 = 0; k0 < II; k0 += 64) {
        int koff = k0 + qS * 32;
#pragma unroll
        for (int c = 0; c < 4; c++) {
            gl2lds16(hbuf + arow[c] + koff + colS, As + wave * 2048 + c * 512);
            gl2lds16(gB0 + (size_t)(c * 16) * II + koff, Bs + wave * 2048 + c * 512);
        }
        __syncthreads();

#pragma unroll
        for (int kk = 0; kk < 2; kk++) {
            bf16x8 a[4], b[4];
            int base = kk * 4096 + qe;
#pragma unroll
            for (int mi = 0; mi < 4; mi++)
                a[mi] = *(const bf16x8*)(As + base + (wm * 64 + mi * 16 + row16) * 32);
#pragma unroll
            for (int ni = 0; ni < 4; ni++)
                b[ni] = *(const bf16x8*)(Bs + base + (wn * 64 + ni * 16 + row16) * 32);
#pragma unroll
            for (int mi = 0; mi < 4; mi++)
#pragma unroll
                for (int ni = 0; ni < 4; ni++)
                    acc[mi][ni] = __builtin_amdgcn_mfma_f32_16x16x32_bf16(a[mi], b[ni], acc[mi][ni], 0, 0, 0);
        }
        __syncthreads();
    }

#pragma unroll
    for (int mi = 0; mi < 4; mi++) {
        int grb = m0 + wm * 64 + mi * 16 + quad * 4;
#pragma unroll
        for (int r = 0; r < 4; r++) {
            int gr = grb + r;
            if (gr >= cnt) continue;
            float* pr = pbuf + (size_t)(base_e + gr) * DD + n0 + wn * 64;
#pragma unroll
            for (int ni = 0; ni < 4; ni++)
                pr[ni * 16 + row16] = acc[mi][ni][r];
        }
    }
}

// tier-2 combine: y[t] = sum of t's 8 routed partials + shared partial.
__global__ __launch_bounds__(256) void combine_kernel(
    const float* __restrict__ pbuf, const int* __restrict__ count,
    const int* __restrict__ poslut, float* __restrict__ y)
{
    int t = blockIdx.x;
    int c4 = threadIdx.x;
    float4 acc = make_float4(0.f, 0.f, 0.f, 0.f);
    int base = 0;
#pragma unroll
    for (int e = 0; e < NE; e++) {
        int p = poslut[e * NTOK + t];
        if (p >= 0) {
            float4 v = ((const float4*)(pbuf + (size_t)(base + p) * DD))[c4];
            acc.x += v.x; acc.y += v.y; acc.z += v.z; acc.w += v.w;
        }
        base += count[e];
    }
    {
        float4 v = ((const float4*)(pbuf + (size_t)(base + t) * DD))[c4];
        acc.x += v.x; acc.y += v.y; acc.z += v.z; acc.w += v.w;
    }
    ((float4*)(y + (size_t)t * DD))[c4] = acc;
}

// ======================= fallback path (round-0 kernels) ====================
__global__ __launch_bounds__(256) void gateup_fb(
    const unsigned short* __restrict__ xbf,
    const float* __restrict__ wg, const float* __restrict__ wu,
    const float* __restrict__ sgw, const float* __restrict__ suw,
    const int* __restrict__ count, const int* __restrict__ list,
    const float* __restrict__ scalebuf, unsigned short* __restrict__ hbuf)
{
    int e = blockIdx.z;
    int cnt = count[e];
    int m0 = blockIdx.x * BM;
    if (m0 >= cnt) return;
    int n0 = blockIdx.y * BN;
    const float* Bg = (e < NE) ? wg + (size_t)e * II * DD : sgw;
    const float* Bu = (e < NE) ? wu + (size_t)e * II * DD : suw;

    __shared__ __align__(16) unsigned short As[BM * LDA];
    __shared__ __align__(16) unsigned short Bgs[BN * LDA];
    __shared__ __align__(16) unsigned short Bus[BN * LDA];
    __shared__ int rowtok[BM];

    int tid = threadIdx.x;
    if (tid < BM) {
        int gr = m0 + tid;
        rowtok[tid] = (gr < cnt) ? list[e * NTOK + gr] : -1;
    }
    __syncthreads();

    int lane = tid & 63, wave = tid >> 6;
    int wm = wave >> 1, wn = wave & 1;
    int row16 = lane & 15, quad = lane >> 4;

    f32x4 accG[4][2], accU[4][2];
#pragma unroll
    for (int mi = 0; mi < 4; mi++)
#pragma unroll
        for (int ni = 0; ni < 2; ni++) {
            accG[mi][ni] = (f32x4){0.f, 0.f, 0.f, 0.f};
            accU[mi][ni] = (f32x4){0.f, 0.f, 0.f, 0.f};
        }

    for (int k0 = 0; k0 < DD; k0 += BK) {
#pragma unroll
        for (int i = 0; i < 2; i++) {
            int c = tid + 256 * i;
            int row = c >> 2, kc = (c & 3) * 8;
            int tok = rowtok[row];
            uint4 v = (tok >= 0) ? *(const uint4*)(xbf + (size_t)tok * DD + k0 + kc)
                                 : make_uint4(0u, 0u, 0u, 0u);
            *(uint4*)(As + row * LDA + kc) = v;
        }
#pragma unroll
        for (int i = 0; i < 2; i++) {
            int c = tid + 256 * i;
            int row = c >> 3, f = (c & 7) * 4;
            float4 vg = *(const float4*)(Bg + (size_t)(n0 + row) * DD + k0 + f);
            float4 vu = *(const float4*)(Bu + (size_t)(n0 + row) * DD + k0 + f);
            *(ushort4*)(Bgs + row * LDA + f) = make_ushort4(f2bf(vg.x), f2bf(vg.y), f2bf(vg.z), f2bf(vg.w));
            *(ushort4*)(Bus + row * LDA + f) = make_ushort4(f2bf(vu.x), f2bf(vu.y), f2bf(vu.z), f2bf(vu.w));
        }
        __syncthreads();

        bf16x8 af[4], bg[2], bu[2];
#pragma unroll
        for (int mi = 0; mi < 4; mi++)
            af[mi] = *(const bf16x8*)(As + (wm * 64 + mi * 16 + row16) * LDA + quad * 8);
#pragma unroll
        for (int ni = 0; ni < 2; ni++) {
            bg[ni] = *(const bf16x8*)(Bgs + (wn * 32 + ni * 16 + row16) * LDA + quad * 8);
            bu[ni] = *(const bf16x8*)(Bus + (wn * 32 + ni * 16 + row16) * LDA + quad * 8);
        }
#pragma unroll
        for (int mi = 0; mi < 4; mi++)
#pragma unroll
            for (int ni = 0; ni < 2; ni++) {
                accG[mi][ni] = __builtin_amdgcn_mfma_f32_16x16x32_bf16(af[mi], bg[ni], accG[mi][ni], 0, 0, 0);
                accU[mi][ni] = __builtin_amdgcn_mfma_f32_16x16x32_bf16(af[mi], bu[ni], accU[mi][ni], 0, 0, 0);
            }
        __syncthreads();
    }

#pragma unroll
    for (int mi = 0; mi < 4; mi++) {
        int mbase = wm * 64 + mi * 16 + quad * 4;
#pragma unroll
        for (int r = 0; r < 4; r++) {
            int gr = m0 + mbase + r;
            if (gr >= cnt) continue;
            float rs = scalebuf[e * NTOK + gr];
            size_t rowoff = ((size_t)e * NTOK + gr) * II + n0;
#pragma unroll
            for (int ni = 0; ni < 2; ni++) {
                int n = wn * 32 + ni * 16 + row16;
                float g = accG[mi][ni][r], u = accU[mi][ni][r];
                float h = g / (1.f + __expf(-g)) * u * rs;
                hbuf[rowoff + n] = f2bf(h);
            }
        }
    }
}

__global__ __launch_bounds__(256) void down_fb(
    const unsigned short* __restrict__ hbuf,
    const float* __restrict__ wd, const float* __restrict__ sdw,
    const int* __restrict__ count, const int* __restrict__ list,
    float* __restrict__ y)
{
    int e = blockIdx.z;
    int cnt = count[e];
    int m0 = blockIdx.x * BM;
    if (m0 >= cnt) return;
    int n0 = blockIdx.y * BN;
    const float* Bp = (e < NE) ? wd + (size_t)e * DD * II : sdw;

    __shared__ __align__(16) unsigned short As[BM * LDA];
    __shared__ __align__(16) unsigned short Bs[BN * LDA];

    int tid = threadIdx.x;
    int lane = tid & 63, wave = tid >> 6;
    int wm = wave >> 1, wn = wave & 1;
    int row16 = lane & 15, quad = lane >> 4;

    f32x4 acc[4][2];
#pragma unroll
    for (int mi = 0; mi < 4; mi++)
#pragma unroll
        for (int ni = 0; ni < 2; ni++) acc[mi][ni] = (f32x4){0.f, 0.f, 0.f, 0.f};

    const unsigned short* Abase = hbuf + ((size_t)e * NTOK + m0) * II;

    for (int k0 = 0; k0 < II; k0 += BK) {
#pragma unroll
        for (int i = 0; i < 2; i++) {
            int c = tid + 256 * i;
            int row = c >> 2, kc = (c & 3) * 8;
            uint4 v = (m0 + row < cnt) ? *(const uint4*)(Abase + (size_t)row * II + k0 + kc)
                                       : make_uint4(0u, 0u, 0u, 0u);
            *(uint4*)(As + row * LDA + kc) = v;
        }
#pragma unroll
        for (int i = 0; i < 2; i++) {
            int c = tid + 256 * i;
            int row = c >> 3, f = (c & 7) * 4;
            float4 v = *(const float4*)(Bp + (size_t)(n0 + row) * II + k0 + f);
            *(ushort4*)(Bs + row * LDA + f) = make_ushort4(f2bf(v.x), f2bf(v.y), f2bf(v.z), f2bf(v.w));
        }
        __syncthreads();

        bf16x8 af[4], bf[2];
#pragma unroll
        for (int mi = 0; mi < 4; mi++)
            af[mi] = *(const bf16x8*)(As + (wm * 64 + mi * 16 + row16) * LDA + quad * 8);
#pragma unroll
        for (int ni = 0; ni < 2; ni++)
            bf[ni] = *(const bf16x8*)(Bs + (wn * 32 + ni * 16 + row16) * LDA + quad * 8);
#pragma unroll
        for (int mi = 0; mi < 4; mi++)
#pragma unroll
            for (int ni = 0; ni < 2; ni++)
                acc[mi][ni] = __builtin_amdgcn_mfma_f32_16x16x32_bf16(af[mi], bf[ni], acc[mi][ni], 0, 0, 0);
        __syncthreads();
    }

#pragma unroll
    for (int mi = 0; mi < 4; mi++) {
        int mbase = wm * 64 + mi * 16 + quad * 4;
#pragma unroll
        for (int r = 0; r < 4; r++) {
            int gr = m0 + mbase + r;
            if (gr >= cnt) continue;
            int t = list[e * NTOK + gr];
#pragma unroll
            for (int ni = 0; ni < 2; ni++) {
                int n = wn * 32 + ni * 16 + row16;
                unsafeAtomicAdd(&y[(size_t)t * DD + n0 + n], acc[mi][ni][r]);
            }
        }
    }
}

extern "C" void kernel_launch(void* const* d_in, const int* in_sizes, int n_in,
                              void* d_out, int out_size, void* d_ws, size_t ws_size,
                              hipStream_t stream)
{
    const float* x    = (const float*)d_in[0];
    const float* gw   = (const float*)d_in[1];
    const float* bias = (const float*)d_in[2];
    const float* wg   = (const float*)d_in[3];
    const float* wu   = (const float*)d_in[4];
    const float* wd   = (const float*)d_in[5];
    const float* sgw  = (const float*)d_in[6];
    const float* suw  = (const float*)d_in[7];
    const float* sdw  = (const float*)d_in[8];
    float* y = (float*)d_out;

    char* ws = (char*)d_ws;
    unsigned short* xbf  = (unsigned short*)(ws + OFF_XBF);
    unsigned short* hbuf = (unsigned short*)(ws + OFF_H);
    unsigned short* wgb  = (unsigned short*)(ws + OFF_WG);
    unsigned short* wub  = (unsigned short*)(ws + OFF_WU);
    unsigned short* wdb  = (unsigned short*)(ws + OFF_WD);
    int*   list     = (int*)(ws + OFF_LIST);
    float* scalebuf = (float*)(ws + OFF_SCALE);
    int*   count    = (int*)(ws + OFF_CNT);
    int*   poslut   = (int*)(ws + OFF_POS);
    float* pbuf     = (float*)(ws + OFF_PBUF);

    bool big = (ws_size >= WS_NEED);
    bool pb  = (ws_size >= WS_NEED2);
    if (!big) {
        list     = (int*)(ws + 36ull * MB);
        scalebuf = (float*)(ws + 36ull * MB + 4ull * NEXP * NTOK);
        count    = (int*)(ws + 36ull * MB + 8ull * NEXP * NTOK);
    }

    // routing scratch aliased into hbuf region (consumed before gateup writes hbuf)
    unsigned int* emask = (unsigned int*)(ws + OFF_H);
    float*        tsc   = (float*)(ws + OFF_H + 4096);

    if (!(big && pb))
        hipMemsetAsync(d_out, 0, (size_t)NTOK * DD * sizeof(float), stream);

    // fused prologue: routing blocks + (big tier only) weight-conversion blocks
    unsigned pro_grid = big ? (ROUTE_BLOCKS + 3 * WCONV_BLOCKS) : ROUTE_BLOCKS;
    prologue_kernel<<<dim3(pro_grid), 256, 0, stream>>>(
        x, gw, bias, xbf, emask, tsc,
        wg, wu, wd, sgw, suw, sdw, wgb, wub, wdb);
    build_lists_kernel<<<dim3(NEXP), 1024, 0, stream>>>(emask, tsc, count, list, scalebuf,
                                                        pb ? poslut : (int*)nullptr);

    if (big) {
        gateup_kernel<<<dim3(NEXP * 8 * 8), 256, 0, stream>>>(
            xbf, wgb, wub, count, list, scalebuf, hbuf);
        if (pb) {
            down_pb_kernel<<<dim3(NEXP * 8 * 8), 256, 0, stream>>>(
                hbuf, wdb, count, pbuf);
            combine_kernel<<<dim3(NTOK), 256, 0, stream>>>(pbuf, count, poslut, y);
        } else {
            down_kernel<<<dim3(NEXP * 8 * 8), 256, 0, stream>>>(
                hbuf, wdb, count, list, y);
        }
    } else {
        gateup_fb<<<dim3(NTOK / BM, II / BN, NEXP), 256, 0, stream>>>(
            xbf, wg, wu, sgw, suw, count, list, scalebuf, hbuf);
        down_fb<<<dim3(NTOK / BM, DD / BN, NEXP), 256, 0, stream>>>(
            hbuf, wd, sdw, count, list, y);
    }
}